// Round 15
// baseline (156.741 us; speedup 1.0000x reference)
//
#include <hip/hip_runtime.h>
#include <hip/hip_bf16.h>

// Raindrop forward, MI355X. B=64 T=128 S=64 O=4 E=64 P=16 A=10 OUT=128.
//  - temporal attention collapsed: (Q K^T) W_s = Q (W_s^T K)  -> no TxT matrix
//  - alpha decomposition: alpha[i][j] = relu(hm10[i]*battn[j] + h[i].v_t + s_t)
//  - r14 structure: persist W1p only; staged adjP partials (no atomics to HBM)
//  - r15: k_attn hbar/hout accumulated via LDS atomicAdd (ds_add_f32) ->
//    phase F reads 1 value/d instead of 6-way collapse per output (x128 redundant)
// ws floats: bidir | masksumInv | brp[16] | sT[8192]
// ws bytes @: WrT 1638464 | catx 1642560 | PEh 1644608 | adjS 1906752 | V 2431040 |
//             W1p 3479616 | adjP 70588480 | Hh 137697344

typedef unsigned short u16;
typedef unsigned int u32;
typedef __attribute__((ext_vector_type(8))) short short8;
typedef __attribute__((ext_vector_type(4))) float f32x4;

#define OFF_BIDIR 131072
#define OFF_MS    135168
#define OFF_BRP   401408
#define OFF_ST    401424
#define BOFF_WRT  1638464u
#define BOFF_CATX 1642560u
#define BOFF_PEH  1644608u
#define BOFF_ADJS 1906752u
#define BOFF_V    2431040u
#define BOFF_W1   3479616u
#define BOFF_ADJP 70588480u
#define BOFF_HH   137697344u

__device__ __forceinline__ u16 f2bf(float f){
  __hip_bfloat16 h = __float2bfloat16(f);
  union { __hip_bfloat16 h; u16 u; } v; v.h = h; return v.u;
}
__device__ __forceinline__ u32 pk2bf(float lo, float hi){
  __hip_bfloat162 h = __float22bfloat162_rn(float2{lo, hi});
  union { __hip_bfloat162 h; u32 u; } v; v.h = h; return v.u;
}
__device__ __forceinline__ float bf2f(u16 h){
  union { u32 u; float f; } v; v.u = ((u32)h) << 16; return v.f;
}

// ---------------- K0: peh/v/sT, bidir, WrT/brp/catx, masksumInv ----------------
__global__ void k_pre(const float* __restrict__ times, const float* __restrict__ mask,
                      const float* __restrict__ Wb, const float* __restrict__ Wrecv,
                      const float* __restrict__ brecv, const float* __restrict__ battn,
                      float* __restrict__ ws_f, char* __restrict__ ws_b) {
  __shared__ float peL[32][17];
  __shared__ float wpe[64][17];
  __shared__ float pm[4][64];
  const int blk = blockIdx.x, tid = threadIdx.x;
  u16* wrt  = (u16*)(ws_b + BOFF_WRT);
  u16* catx = (u16*)(ws_b + BOFF_CATX);
  u16* peh  = (u16*)(ws_b + BOFF_PEH);
  u16* vv   = (u16*)(ws_b + BOFF_V);
  float* ST = ws_f + OFF_ST;
  if (blk < 256) {                     // PE (bf16) + v_t + s_t for 32 bt rows
    #pragma unroll
    for (int r = 0; r < 2; ++r) {
      int id = blk * 512 + r * 256 + tid;
      int bt = id >> 4, k = id & 15;
      float tv = times[bt];
      int kk = k & 7;
      float fr = expf(-(float)kk * 1.1512925465f); // ln(1e4)/8
      float ang = tv * fr;
      float v = (k < 8) ? sinf(ang) : cosf(ang);
      peh[id] = f2bf(v);
      peL[r*16 + (tid >> 4)][k] = v;
    }
    #pragma unroll
    for (int q = 0; q < 4; ++q) {
      int idx = q * 256 + tid;
      wpe[idx >> 4][idx & 15] = Wrecv[(idx >> 4)*26 + 10 + (idx & 15)];
    }
    __syncthreads();
    {
      int btl = tid >> 3, e0 = (tid & 7) * 8;
      float acc[8];
      #pragma unroll
      for (int i = 0; i < 8; ++i) acc[i] = 0.f;
      #pragma unroll
      for (int k = 0; k < 16; ++k) {
        float p = peL[btl][k];
        #pragma unroll
        for (int i = 0; i < 8; ++i) acc[i] += wpe[e0 + i][k] * p;
      }
      u32* dst = (u32*)&vv[(blk*32 + btl)*64 + e0];
      #pragma unroll
      for (int p = 0; p < 4; ++p) dst[p] = pk2bf(acc[2*p], acc[2*p+1]);
      if (tid < 32) {
        float s = 0.f;
        #pragma unroll
        for (int k = 0; k < 16; ++k) s += brecv[10 + k] * peL[tid][k];
        ST[blk*32 + tid] = s;
      }
    }
  } else if (blk < 260) {              // bidir = Wb @ Wb^T (4 blocks)
    float* bidir = ws_f + OFF_BIDIR;
    int q = blk - 256;
    for (int rr = 0; rr < 4; ++rr) {
      int idx = (q*4 + rr) * 256 + tid;
      int i = idx >> 6, j = idx & 63;
      float acc = 0.f;
      for (int e = 0; e < 64; ++e) acc += Wb[i*64+e] * Wb[j*64+e];
      bidir[idx] = acc;
    }
  } else if (blk == 260) {             // WrT, brp (pad16), catx
    for (int r = 0; r < 8; ++r) {
      int idx = r * 256 + tid;
      int d = idx >> 6, e = idx & 63;
      wrt[idx] = (d < 26) ? f2bf(Wrecv[e*26 + d]) : (u16)0;
    }
    if (tid < 16) ws_f[OFF_BRP + tid] = (tid < 10) ? brecv[tid] : 0.f;
    #pragma unroll
    for (int i = 0; i < 4; ++i) {
      int idx = i * 256 + tid;
      int j = idx >> 4, d = idx & 15;
      catx[idx] = (d < 10) ? f2bf(battn[j*10 + d]) : ((d == 10) ? f2bf(1.f) : (u16)0);
    }
  } else {                             // masksumInv[b][i]
    int b = blk - 261;
    int i = tid & 63, q = tid >> 6;
    float s = 0.f;
    for (int t = q*32; t < q*32 + 32; ++t) s += mask[(b*128 + t)*64 + i];
    pm[q][i] = s;
    __syncthreads();
    if (tid < 64)
      (ws_f + OFF_MS)[b*64 + tid] =
          1.0f / (pm[0][tid] + pm[1][tid] + pm[2][tid] + pm[3][tid]);
  }
}

// ---------------- K1: alpha partials (staged) + persist W1p ----------------
__global__ __launch_bounds__(256)
void k_adj(const float* __restrict__ x, const float* __restrict__ mask,
           const float* __restrict__ Wobs, float* __restrict__ ws_f,
           char* __restrict__ ws_b) {
  __shared__ __align__(16) u16 hA[64][72];
  __shared__ __align__(16) u16 hmA[64][24];

  const int tid = threadIdx.x;
  const int b = blockIdx.y, tc = blockIdx.x;
  const int w = tid >> 6, l = tid & 63, lr = l & 15, lq = l >> 4, kb = lq * 8;
  const int i0 = 16*w + lq*4;
  const u16* wrt  = (const u16*)(ws_b + BOFF_WRT);
  const u16* catx = (const u16*)(ws_b + BOFF_CATX);
  const u16* vv   = (const u16*)(ws_b + BOFF_V);
  const float* brp = ws_f + OFF_BRP;
  const float* ST = ws_f + OFF_ST;
  const float* bidirG = ws_f + OFF_BIDIR;

  const short8 z8 = (short8){0,0,0,0,0,0,0,0};
  const bool lowk = (lq < 2);
  short8 w0 = z8, w1 = z8;
  if (lr < 10) {
    const u16* wr = wrt + lr * 64;
    w0 = *(const short8*)&wr[kb];
    w1 = *(const short8*)&wr[32 + kb];
  }
  short8 bc[4];
  #pragma unroll
  for (int n = 0; n < 4; ++n)
    bc[n] = lowk ? *(const short8*)&catx[(16*n + lr)*16 + lq*8] : z8;
  float4 bv = *(const float4*)&brp[lq*4];
  float bidirR[4][4];
  #pragma unroll
  for (int n = 0; n < 4; ++n)
    #pragma unroll
    for (int reg = 0; reg < 4; ++reg)
      bidirR[n][reg] = bidirG[((i0+reg) << 6) + 16*n + lr];

  f32x4 asum[4];
  #pragma unroll
  for (int n = 0; n < 4; ++n) asum[n] = (f32x4){0.f,0.f,0.f,0.f};

  const int e4 = tid & 15, sg = tid >> 4;

  for (int tt = 0; tt < 8; ++tt) {
    int t = tc * 8 + tt;
    int base = b * 128 + t;
    short8 av0 = z8, av1 = z8;
    if (lr == 10) {
      av0 = *(const short8*)&vv[base*64 + kb];
      av1 = *(const short8*)&vv[base*64 + 32 + kb];
    }
    float st = ST[base];
    { // P0: h build -> hA (LDS only)
      float4 mk4 = *(const float4*)&mask[base*64 + sg*4];
      float mks[4] = {mk4.x, mk4.y, mk4.z, mk4.w};
      #pragma unroll
      for (int si = 0; si < 4; ++si) {
        int s = sg*4 + si;
        float4 xv = *(const float4*)&x[base*256 + s*4];
        float xo[4] = {xv.x, xv.y, xv.z, xv.w};
        float ax = 0.f, ay = 0.f, az = 0.f, aw = 0.f;
        #pragma unroll
        for (int o = 0; o < 4; ++o) {
          float4 wv = *(const float4*)&Wobs[(s*4+o)*64 + e4*4];
          ax += xo[o]*wv.x; ay += xo[o]*wv.y; az += xo[o]*wv.z; aw += xo[o]*wv.w;
        }
        float mk = mks[si];
        uint2 p;
        p.x = pk2bf(fmaxf(ax,0.f)*mk, fmaxf(ay,0.f)*mk);
        p.y = pk2bf(fmaxf(az,0.f)*mk, fmaxf(aw,0.f)*mk);
        *(uint2*)&hA[s][e4*4] = p;
      }
    }
    __syncthreads();
    { // P1: hmx
      short8 a0 = (lr < 10) ? w0 : av0;
      short8 a1 = (lr < 10) ? w1 : av1;
      f32x4 acc = (f32x4){0.f,0.f,0.f,0.f};
      short8 b0 = *(const short8*)&hA[16*w + lr][kb];
      short8 b1 = *(const short8*)&hA[16*w + lr][32 + kb];
      acc = __builtin_amdgcn_mfma_f32_16x16x32_bf16(a0, b0, acc, 0, 0, 0);
      acc = __builtin_amdgcn_mfma_f32_16x16x32_bf16(a1, b1, acc, 0, 0, 0);
      uint2 qq;
      qq.x = pk2bf(acc[0]+bv.x, acc[1]+bv.y);
      qq.y = pk2bf(acc[2]+bv.z, acc[3]+bv.w);
      *(uint2*)&hmA[16*w + lr][lq*4] = qq;
    }
    __syncthreads();
    { // P2: alpha; accumulate asum; write lane-packed w1
      short8 am = lowk ? *(const short8*)&hmA[16*w + lr][lq*8] : z8;
      u32 w1u[8];
      #pragma unroll
      for (int n = 0; n < 4; ++n) {
        f32x4 z = (f32x4){st, st, st, st};
        z = __builtin_amdgcn_mfma_f32_16x16x32_bf16(am, bc[n], z, 0, 0, 0);
        float w1v[4];
        #pragma unroll
        for (int reg = 0; reg < 4; ++reg) {
          float al = fmaxf(z[reg], 0.f);
          asum[n][reg] += al;
          w1v[reg] = al * bidirR[n][reg];
        }
        w1u[2*n]   = pk2bf(w1v[0], w1v[1]);
        w1u[2*n+1] = pk2bf(w1v[2], w1v[3]);
      }
      u16* w1g = (u16*)(ws_b + BOFF_W1) + (size_t)base * 4096 + tid * 16;
      uint4 A, B;
      A.x = w1u[0]; A.y = w1u[1]; A.z = w1u[2]; A.w = w1u[3];
      B.x = w1u[4]; B.y = w1u[5]; B.z = w1u[6]; B.w = w1u[7];
      *(uint4*)&w1g[0] = A;
      *(uint4*)&w1g[8] = B;
    }
    __syncthreads();
  }
  { // staged partials: adjP[tc][b][tid*16 + n*4 + reg], coalesced float4 x4
    float* adjP = (float*)(ws_b + BOFF_ADJP) + (((size_t)tc * 64 + b) << 12) + tid * 16;
    #pragma unroll
    for (int n = 0; n < 4; ++n) {
      float4 A;
      A.x = asum[n][0]; A.y = asum[n][1]; A.z = asum[n][2]; A.w = asum[n][3];
      *(float4*)&adjP[n * 4] = A;
    }
  }
}

// ---------------- K1b: adjS = bf16(sum_tc adjP * msInv) ----------------
__global__ __launch_bounds__(256)
void k_scale(const float* __restrict__ ws_f, char* __restrict__ ws_b) {
  const int b = blockIdx.x, tid = threadIdx.x;
  const int w = tid >> 6, l = tid & 63, lr = l & 15, lq = l >> 4;
  const int i0 = 16*w + lq*4;
  const float* msI = ws_f + OFF_MS + b * 64;
  u16* as_ = (u16*)(ws_b + BOFF_ADJS) + (size_t)b * 4096;

  float S[16];
  #pragma unroll
  for (int k = 0; k < 16; ++k) S[k] = 0.f;
  for (int tc = 0; tc < 16; ++tc) {
    const float4* src = (const float4*)
        ((const float*)(ws_b + BOFF_ADJP) + (((size_t)tc * 64 + b) << 12) + tid * 16);
    #pragma unroll
    for (int n = 0; n < 4; ++n) {
      float4 v = src[n];
      S[n*4+0] += v.x; S[n*4+1] += v.y; S[n*4+2] += v.z; S[n*4+3] += v.w;
    }
  }
  float msr[4];
  #pragma unroll
  for (int reg = 0; reg < 4; ++reg) msr[reg] = msI[i0 + reg];
  #pragma unroll
  for (int n = 0; n < 4; ++n)
    #pragma unroll
    for (int reg = 0; reg < 4; ++reg)
      as_[(i0 + reg) * 64 + 16*n + lr] = f2bf(S[n*4 + reg] * msr[reg]);
}

// ---------------- K2: h rebuild + prop1 + prop2 (loads W1p/adjS) ----------------
__global__ __launch_bounds__(256, 4)
void k_main(const float* __restrict__ x, const float* __restrict__ mask,
            const float* __restrict__ Wobs, const float* __restrict__ ws_f,
            const char* __restrict__ ws_b, u16* __restrict__ Hh) {
  __shared__ __align__(16) char smem[36864];
  u16 (*h1L)[72] = (u16 (*)[72])(smem);           // h1T [e][i]
  u16 (*hT)[72]  = (u16 (*)[72])(smem + 9216);    // h^T [e][s]
  u16 (*wA)[72]  = (u16 (*)[72])(smem + 18432);   // w1 [i][j]
  u16 (*adjS)[72]= (u16 (*)[72])(smem + 27648);

  const int tid = threadIdx.x;
  const int t = blockIdx.x, b = blockIdx.y;
  const int w = tid >> 6, l = tid & 63, lr = l & 15, lq = l >> 4, kb = lq * 8;
  const int base = b * 128 + t;
  const int i0 = 16*w + lq*4;

  // prefetch W1p + adjS (coalesced)
  const uint4* ag = (const uint4*)(ws_b + BOFF_ADJS + (size_t)b * 8192);
  uint4 g0 = ag[2*tid], g1 = ag[2*tid + 1];
  const uint4* wp = (const uint4*)((const u16*)(ws_b + BOFF_W1) + (size_t)base * 4096);
  uint4 wp0 = wp[2*tid], wp1 = wp[2*tid + 1];

  { // P0: h rebuild -> hT directly; unpack wA; stage adjS
    const int e4 = tid & 15, sg = tid >> 4;
    float4 mk4 = *(const float4*)&mask[base*64 + sg*4];
    float mks[4] = {mk4.x, mk4.y, mk4.z, mk4.w};
    u16 hv[4][4];
    #pragma unroll
    for (int si = 0; si < 4; ++si) {
      int s = sg*4 + si;
      float4 xv = *(const float4*)&x[base*256 + s*4];
      float xo[4] = {xv.x, xv.y, xv.z, xv.w};
      float ax = 0.f, ay = 0.f, az = 0.f, aw = 0.f;
      #pragma unroll
      for (int o = 0; o < 4; ++o) {
        float4 wv = *(const float4*)&Wobs[(s*4+o)*64 + e4*4];
        ax += xo[o]*wv.x; ay += xo[o]*wv.y; az += xo[o]*wv.z; aw += xo[o]*wv.w;
      }
      float mk = mks[si];
      u32 plo = pk2bf(fmaxf(ax,0.f)*mk, fmaxf(ay,0.f)*mk);
      u32 phi = pk2bf(fmaxf(az,0.f)*mk, fmaxf(aw,0.f)*mk);
      hv[si][0] = (u16)plo; hv[si][1] = (u16)(plo >> 16);
      hv[si][2] = (u16)phi; hv[si][3] = (u16)(phi >> 16);
    }
    #pragma unroll
    for (int k = 0; k < 4; ++k) {
      uint2 q;
      q.x = (u32)hv[0][k] | ((u32)hv[1][k] << 16);
      q.y = (u32)hv[2][k] | ((u32)hv[3][k] << 16);
      *(uint2*)&hT[e4*4 + k][sg*4] = q;
    }
    u32 q[8] = {wp0.x, wp0.y, wp0.z, wp0.w, wp1.x, wp1.y, wp1.z, wp1.w};
    #pragma unroll
    for (int n = 0; n < 4; ++n) {
      int j = 16*n + lr;
      u32 lo = q[2*n], hi = q[2*n+1];
      wA[i0+0][j] = (u16)lo; wA[i0+1][j] = (u16)(lo >> 16);
      wA[i0+2][j] = (u16)hi; wA[i0+3][j] = (u16)(hi >> 16);
    }
    int idx0 = 2*tid, idx1 = 2*tid + 1;
    *(uint4*)&adjS[idx0 >> 3][(idx0 & 7) * 8] = g0;
    *(uint4*)&adjS[idx1 >> 3][(idx1 & 7) * 8] = g1;
  }
  __syncthreads();

  { // P1: h1 = relu(w1 @ h) -> h1L
    short8 aw0 = *(const short8*)&wA[16*w + lr][kb];
    short8 aw1 = *(const short8*)&wA[16*w + lr][32 + kb];
    #pragma unroll
    for (int n = 0; n < 4; ++n) {
      f32x4 acc = (f32x4){0.f,0.f,0.f,0.f};
      short8 b0 = *(const short8*)&hT[16*n + lr][kb];
      short8 b1 = *(const short8*)&hT[16*n + lr][32 + kb];
      acc = __builtin_amdgcn_mfma_f32_16x16x32_bf16(aw0, b0, acc, 0, 0, 0);
      acc = __builtin_amdgcn_mfma_f32_16x16x32_bf16(aw1, b1, acc, 0, 0, 0);
      int e = 16*n + lr;
      uint2 pp;
      pp.x = pk2bf(fmaxf(acc[0],0.f), fmaxf(acc[1],0.f));
      pp.y = pk2bf(fmaxf(acc[2],0.f), fmaxf(acc[3],0.f));
      *(uint2*)&h1L[e][i0] = pp;
    }
  }
  __syncthreads();

  { // P2: w2 = w1 (.) adjS; h2 = relu(w2 @ h1) -> Hh
    int row = 16*w + lr;
    union { short8 v; u16 h[8]; u32 u[4]; } uw0, uw1, ud0, ud1, oa, ob;
    uw0.v = *(const short8*)&wA[row][kb];
    uw1.v = *(const short8*)&wA[row][32 + kb];
    ud0.v = *(const short8*)&adjS[row][kb];
    ud1.v = *(const short8*)&adjS[row][32 + kb];
    #pragma unroll
    for (int k = 0; k < 4; ++k) {
      oa.u[k] = pk2bf(bf2f(uw0.h[2*k])*bf2f(ud0.h[2*k]),
                      bf2f(uw0.h[2*k+1])*bf2f(ud0.h[2*k+1]));
      ob.u[k] = pk2bf(bf2f(uw1.h[2*k])*bf2f(ud1.h[2*k]),
                      bf2f(uw1.h[2*k+1])*bf2f(ud1.h[2*k+1]));
    }
    short8 a20 = oa.v, a21 = ob.v;
    size_t obase = ((size_t)b * 64) * 8192 + (size_t)t * 64;
    #pragma unroll
    for (int n = 0; n < 4; ++n) {
      f32x4 acc = (f32x4){0.f,0.f,0.f,0.f};
      short8 b0 = *(const short8*)&h1L[16*n + lr][kb];
      short8 b1 = *(const short8*)&h1L[16*n + lr][32 + kb];
      acc = __builtin_amdgcn_mfma_f32_16x16x32_bf16(a20, b0, acc, 0, 0, 0);
      acc = __builtin_amdgcn_mfma_f32_16x16x32_bf16(a21, b1, acc, 0, 0, 0);
      int e = 16*n + lr;
      u32 p0 = pk2bf(fmaxf(acc[0],0.f), fmaxf(acc[1],0.f));
      u32 p1 = pk2bf(fmaxf(acc[2],0.f), fmaxf(acc[3],0.f));
      Hh[obase + (size_t)(i0+0) * 8192 + e] = (u16)p0;
      Hh[obase + (size_t)(i0+1) * 8192 + e] = (u16)(p0 >> 16);
      Hh[obase + (size_t)(i0+2) * 8192 + e] = (u16)p1;
      Hh[obase + (size_t)(i0+3) * 8192 + e] = (u16)(p1 >> 16);
    }
  }
}

// ---------------- K3: collapsed temporal attention (512 thr; LDS-atomic hbar/hout) ----------------
#define HTP 82

__global__ __launch_bounds__(512)
void k_attn(const char* __restrict__ ws_b, const u16* __restrict__ Hh,
            const float* __restrict__ Wq, const float* __restrict__ bq,
            const float* __restrict__ Wk, const float* __restrict__ bk,
            const float* __restrict__ Ws, const float* __restrict__ bs,
            const float* __restrict__ Wemb, const float* __restrict__ bemb,
            float* __restrict__ out) {
  __shared__ u16 Ht[128][HTP];
  __shared__ u16 peB[128][18];
  __shared__ float wsL[128];
  __shared__ float hbar[80];
  __shared__ float hout[80];
  __shared__ float pK[8][10];
  __shared__ float qvL[80];
  __shared__ float pC[4][128];
  __shared__ float bb[128];
  __shared__ float red[4];
  __shared__ float cstL, sWL;

  const int tid = threadIdx.x;
  const int s = blockIdx.x, b = blockIdx.y;
  const float scale = 0.111803398875f; // 1/sqrt(80)
  const u16* peh = (const u16*)(ws_b + BOFF_PEH);

  const u16* src = Hh + ((size_t)b * 64 + s) * 8192;
  #pragma unroll
  for (int r = 0; r < 2; ++r) {
    int id = r * 512 + tid;
    int tt = id >> 3, c = (id & 7) * 8;
    uint4 q = *(const uint4*)&src[tt * 64 + c];
    u32* dst = (u32*)&Ht[tt][c];
    dst[0] = q.x; dst[1] = q.y; dst[2] = q.z; dst[3] = q.w;
  }
  #pragma unroll
  for (int r = 0; r < 2; ++r) {
    int id = r * 512 + tid;
    u32 pv = ((const u32*)(peh + (size_t)b * 2048))[id];
    *(u32*)&peB[id >> 3][(id & 7) * 2] = pv;
  }
  if (tid < 128) wsL[tid] = Ws[tid];
  if (tid >= 128 && tid < 208) hbar[tid - 128] = 0.f;
  if (tid >= 208 && tid < 288) hout[tid - 208] = 0.f;
  __syncthreads();

  // Phase A: hbar += chunk partials (6 t-chunks of ~22, LDS atomic)
  if (tid < 480) {
    int d = tid % 80, c = tid / 80;
    int t0 = c * 22, t1 = (t0 + 22 > 128) ? 128 : t0 + 22;
    float a0 = 0.f, a1 = 0.f, a2 = 0.f, a3 = 0.f;
    int t = t0;
    if (d < 64) {
      for (; t + 4 <= t1; t += 4) {
        a0 += wsL[t]   * bf2f(Ht[t][d]);
        a1 += wsL[t+1] * bf2f(Ht[t+1][d]);
        a2 += wsL[t+2] * bf2f(Ht[t+2][d]);
        a3 += wsL[t+3] * bf2f(Ht[t+3][d]);
      }
      for (; t < t1; ++t) a0 += wsL[t] * bf2f(Ht[t][d]);
    } else {
      int k = d - 64;
      for (; t + 4 <= t1; t += 4) {
        a0 += wsL[t]   * bf2f(peB[t][k]);
        a1 += wsL[t+1] * bf2f(peB[t+1][k]);
        a2 += wsL[t+2] * bf2f(peB[t+2][k]);
        a3 += wsL[t+3] * bf2f(peB[t+3][k]);
      }
      for (; t < t1; ++t) a0 += wsL[t] * bf2f(peB[t][k]);
    }
    atomicAdd(&hbar[d], (a0 + a1) + (a2 + a3));
  } else if (tid == 480) {
    float a0 = 0.f, a1 = 0.f, a2 = 0.f, a3 = 0.f;
    for (int t = 0; t < 128; t += 4) {
      a0 += wsL[t]; a1 += wsL[t+1]; a2 += wsL[t+2]; a3 += wsL[t+3];
    }
    sWL = (a0 + a1) + (a2 + a3);
  }
  __syncthreads();

  // pK partials from hbar (1 read per element)
  if (tid < 80) {
    int a = tid % 10, c = tid / 10;
    float a0 = 0.f, a1 = 0.f;
    #pragma unroll
    for (int i = 0; i < 10; i += 2) {
      int d = c * 10 + i;
      a0 += hbar[d]   * Wk[d * 10 + a];
      a1 += hbar[d+1] * Wk[(d+1) * 10 + a];
    }
    pK[c][a] = a0 + a1;
  }
  __syncthreads();

  if (tid <= 80) {
    float kt[10];
    #pragma unroll
    for (int a = 0; a < 10; ++a) {
      float acc = sWL * bk[a];
      #pragma unroll
      for (int c = 0; c < 8; ++c) acc += pK[c][a];
      kt[a] = acc;
    }
    if (tid < 80) {
      float a0 = 0.f, a1 = 0.f;
      #pragma unroll
      for (int a = 0; a < 10; a += 2) {
        a0 += Wq[tid * 10 + a] * kt[a];
        a1 += Wq[tid * 10 + a + 1] * kt[a + 1];
      }
      qvL[tid] = a0 + a1;
    } else {
      float cq = 0.f;
      #pragma unroll
      for (int a = 0; a < 10; ++a) cq += bq[a] * kt[a];
      cstL = scale * cq + bs[0];
    }
  }
  __syncthreads();

  // Phase C: beta partials over 4 d-quarters
  {
    int t = tid & 127, q = tid >> 7;
    float a0 = 0.f, a1 = 0.f, a2 = 0.f, a3 = 0.f;
    const u32* row = (const u32*)&Ht[t][0];
    if (q == 0) {
      #pragma unroll
      for (int i = 0; i < 10; i += 2) {
        u32 p0 = row[i], p1 = row[i+1];
        a0 += bf2f((u16)p0) * qvL[2*i]   + bf2f((u16)(p0 >> 16)) * qvL[2*i+1];
        a1 += bf2f((u16)p1) * qvL[2*i+2] + bf2f((u16)(p1 >> 16)) * qvL[2*i+3];
      }
    } else if (q == 1) {
      #pragma unroll
      for (int i = 10; i < 20; i += 2) {
        u32 p0 = row[i], p1 = row[i+1];
        a0 += bf2f((u16)p0) * qvL[2*i]   + bf2f((u16)(p0 >> 16)) * qvL[2*i+1];
        a1 += bf2f((u16)p1) * qvL[2*i+2] + bf2f((u16)(p1 >> 16)) * qvL[2*i+3];
      }
    } else if (q == 2) {
      #pragma unroll
      for (int i = 20; i < 32; i += 4) {
        u32 p0 = row[i], p1 = row[i+1], p2 = row[i+2], p3 = row[i+3];
        a0 += bf2f((u16)p0) * qvL[2*i]   + bf2f((u16)(p0 >> 16)) * qvL[2*i+1];
        a1 += bf2f((u16)p1) * qvL[2*i+2] + bf2f((u16)(p1 >> 16)) * qvL[2*i+3];
        a2 += bf2f((u16)p2) * qvL[2*i+4] + bf2f((u16)(p2 >> 16)) * qvL[2*i+5];
        a3 += bf2f((u16)p3) * qvL[2*i+6] + bf2f((u16)(p3 >> 16)) * qvL[2*i+7];
      }
    } else {
      #pragma unroll
      for (int k = 0; k < 16; k += 4) {
        a0 += bf2f(peB[t][k])   * qvL[64 + k];
        a1 += bf2f(peB[t][k+1]) * qvL[65 + k];
        a2 += bf2f(peB[t][k+2]) * qvL[66 + k];
        a3 += bf2f(peB[t][k+3]) * qvL[67 + k];
      }
    }
    pC[q][t] = (a0 + a1) + (a2 + a3);
  }
  __syncthreads();

  if (tid < 128) {
    float v = scale * (pC[0][tid] + pC[1][tid] + pC[2][tid] + pC[3][tid]) + cstL;
    bb[tid] = v;
    float mm = v;
    #pragma unroll
    for (int off = 32; off; off >>= 1) mm = fmaxf(mm, __shfl_xor(mm, off));
    if ((tid & 63) == 0) red[tid >> 6] = mm;
  }
  __syncthreads();
  float mx = fmaxf(red[0], red[1]);
  if (tid < 128) {
    float ev = expf(bb[tid] - mx);
    bb[tid] = ev;
    float ss = ev;
    #pragma unroll
    for (int off = 32; off; off >>= 1) ss += __shfl_xor(ss, off);
    if ((tid & 63) == 0) red[2 + (tid >> 6)] = ss;
  }
  __syncthreads();

  // Phase E: hout += chunk partials (LDS atomic)
  if (tid < 480) {
    int d = tid % 80, c = tid / 80;
    int t0 = c * 22, t1 = (t0 + 22 > 128) ? 128 : t0 + 22;
    float a0 = 0.f, a1 = 0.f, a2 = 0.f, a3 = 0.f;
    int t = t0;
    if (d < 64) {
      for (; t + 4 <= t1; t += 4) {
        a0 += bb[t]   * bf2f(Ht[t][d]);
        a1 += bb[t+1] * bf2f(Ht[t+1][d]);
        a2 += bb[t+2] * bf2f(Ht[t+2][d]);
        a3 += bb[t+3] * bf2f(Ht[t+3][d]);
      }
      for (; t < t1; ++t) a0 += bb[t] * bf2f(Ht[t][d]);
    } else {
      int k = d - 64;
      for (; t + 4 <= t1; t += 4) {
        a0 += bb[t]   * bf2f(peB[t][k]);
        a1 += bb[t+1] * bf2f(peB[t+1][k]);
        a2 += bb[t+2] * bf2f(peB[t+2][k]);
        a3 += bb[t+3] * bf2f(peB[t+3][k]);
      }
      for (; t < t1; ++t) a0 += bb[t] * bf2f(peB[t][k]);
    }
    atomicAdd(&hout[d], (a0 + a1) + (a2 + a3));
  }
  __syncthreads();

  // Phase F: out partials over 4 d-chunks of 20 (1 hout read per element)
  {
    int o = tid & 127, q = tid >> 7;
    int d0 = q * 20;
    float a0 = 0.f, a1 = 0.f, a2 = 0.f, a3 = 0.f;
    #pragma unroll
    for (int i = 0; i < 20; i += 4) {
      int d = d0 + i;
      a0 += hout[d]   * Wemb[d * 128 + o];
      a1 += hout[d+1] * Wemb[(d+1) * 128 + o];
      a2 += hout[d+2] * Wemb[(d+2) * 128 + o];
      a3 += hout[d+3] * Wemb[(d+3) * 128 + o];
    }
    pC[q][o] = (a0 + a1) + (a2 + a3);
  }
  __syncthreads();
  if (tid < 128) {
    float rdenom = 1.0f / (red[2] + red[3]);
    out[(((size_t)b * 64 + s) << 7) + tid] =
        bemb[tid] + (pC[0][tid] + pC[1][tid] + pC[2][tid] + pC[3][tid]) * rdenom;
  }
}

extern "C" void kernel_launch(void* const* d_in, const int* in_sizes, int n_in,
                              void* d_out, int out_size, void* d_ws, size_t ws_size,
                              hipStream_t stream) {
  (void)in_sizes; (void)n_in; (void)out_size; (void)ws_size;
  const float* x     = (const float*)d_in[0];
  const float* times = (const float*)d_in[1];
  const float* mask  = (const float*)d_in[2];
  const float* Wobs  = (const float*)d_in[3];
  const float* Wattn = (const float*)d_in[4];
  const float* Wrecv = (const float*)d_in[5];
  const float* brecv = (const float*)d_in[6];
  const float* Wb    = (const float*)d_in[7];
  const float* Wq    = (const float*)d_in[8];
  const float* bq    = (const float*)d_in[9];
  const float* Wk    = (const float*)d_in[10];
  const float* bk    = (const float*)d_in[11];
  const float* Ws    = (const float*)d_in[12];
  const float* bs    = (const float*)d_in[13];
  const float* Wemb  = (const float*)d_in[14];
  const float* bemb  = (const float*)d_in[15];
  float* out = (float*)d_out;
  float* ws_f = (float*)d_ws;
  char* ws_b = (char*)d_ws;
  u16* Hh = (u16*)(ws_b + BOFF_HH);

  k_pre<<<325, 256, 0, stream>>>(times, mask, Wb, Wrecv, brecv, Wattn, ws_f, ws_b);
  k_adj<<<dim3(16, 64), 256, 0, stream>>>(x, mask, Wobs, ws_f, ws_b);
  k_scale<<<64, 256, 0, stream>>>(ws_f, ws_b);
  k_main<<<dim3(128, 64), 256, 0, stream>>>(x, mask, Wobs, ws_f, ws_b, Hh);
  k_attn<<<dim3(64, 64), 512, 0, stream>>>(ws_b, Hh, Wq, bq, Wk, bk, Ws, bs, Wemb, bemb, out);
}

// Round 16
// 138.277 us; speedup vs baseline: 1.1335x; 1.1335x over previous
//
#include <hip/hip_runtime.h>
#include <hip/hip_bf16.h>

// Raindrop forward, MI355X. B=64 T=128 S=64 O=4 E=64 P=16 A=10 OUT=128.
//  - temporal attention collapsed: (Q K^T) W_s = Q (W_s^T K)  -> no TxT matrix
//  - alpha decomposition: alpha[i][j] = relu(hm10[i]*battn[j] + h[i].v_t + s_t)
//  - r16: r12 slim k_main (prop-only) + lane-major hTg (coalesced both sides) +
//    staged adjP partials (no atomics; aliases Hh region, consumed before Hh write)
//  - k_attn: r14 version (partial matrices; r15 LDS-atomics reverted)
// ws floats: bidir | masksumInv | brp[16] | sT[8192]
// ws bytes @: WrT 1638464 | catx 1642560 | PEh 1644608 | adjS 1906752 | V 2431040 |
//             W1p 3479616 | hTg 70588480 | Hh 137697344 | adjP=alias(Hh)

typedef unsigned short u16;
typedef unsigned int u32;
typedef __attribute__((ext_vector_type(8))) short short8;
typedef __attribute__((ext_vector_type(4))) float f32x4;

#define OFF_BIDIR 131072
#define OFF_MS    135168
#define OFF_BRP   401408
#define OFF_ST    401424
#define BOFF_WRT  1638464u
#define BOFF_CATX 1642560u
#define BOFF_PEH  1644608u
#define BOFF_ADJS 1906752u
#define BOFF_V    2431040u
#define BOFF_W1   3479616u
#define BOFF_HT   70588480u
#define BOFF_HH   137697344u
#define BOFF_ADJP 137697344u   // alias: dead before Hh is written

__device__ __forceinline__ u16 f2bf(float f){
  __hip_bfloat16 h = __float2bfloat16(f);
  union { __hip_bfloat16 h; u16 u; } v; v.h = h; return v.u;
}
__device__ __forceinline__ u32 pk2bf(float lo, float hi){
  __hip_bfloat162 h = __float22bfloat162_rn(float2{lo, hi});
  union { __hip_bfloat162 h; u32 u; } v; v.h = h; return v.u;
}
__device__ __forceinline__ float bf2f(u16 h){
  union { u32 u; float f; } v; v.u = ((u32)h) << 16; return v.f;
}

// ---------------- K0: peh/v/sT, bidir, WrT/brp/catx, masksumInv ----------------
__global__ void k_pre(const float* __restrict__ times, const float* __restrict__ mask,
                      const float* __restrict__ Wb, const float* __restrict__ Wrecv,
                      const float* __restrict__ brecv, const float* __restrict__ battn,
                      float* __restrict__ ws_f, char* __restrict__ ws_b) {
  __shared__ float peL[32][17];
  __shared__ float wpe[64][17];
  __shared__ float pm[4][64];
  const int blk = blockIdx.x, tid = threadIdx.x;
  u16* wrt  = (u16*)(ws_b + BOFF_WRT);
  u16* catx = (u16*)(ws_b + BOFF_CATX);
  u16* peh  = (u16*)(ws_b + BOFF_PEH);
  u16* vv   = (u16*)(ws_b + BOFF_V);
  float* ST = ws_f + OFF_ST;
  if (blk < 256) {                     // PE (bf16) + v_t + s_t for 32 bt rows
    #pragma unroll
    for (int r = 0; r < 2; ++r) {
      int id = blk * 512 + r * 256 + tid;
      int bt = id >> 4, k = id & 15;
      float tv = times[bt];
      int kk = k & 7;
      float fr = expf(-(float)kk * 1.1512925465f); // ln(1e4)/8
      float ang = tv * fr;
      float v = (k < 8) ? sinf(ang) : cosf(ang);
      peh[id] = f2bf(v);
      peL[r*16 + (tid >> 4)][k] = v;
    }
    #pragma unroll
    for (int q = 0; q < 4; ++q) {
      int idx = q * 256 + tid;
      wpe[idx >> 4][idx & 15] = Wrecv[(idx >> 4)*26 + 10 + (idx & 15)];
    }
    __syncthreads();
    {
      int btl = tid >> 3, e0 = (tid & 7) * 8;
      float acc[8];
      #pragma unroll
      for (int i = 0; i < 8; ++i) acc[i] = 0.f;
      #pragma unroll
      for (int k = 0; k < 16; ++k) {
        float p = peL[btl][k];
        #pragma unroll
        for (int i = 0; i < 8; ++i) acc[i] += wpe[e0 + i][k] * p;
      }
      u32* dst = (u32*)&vv[(blk*32 + btl)*64 + e0];
      #pragma unroll
      for (int p = 0; p < 4; ++p) dst[p] = pk2bf(acc[2*p], acc[2*p+1]);
      if (tid < 32) {
        float s = 0.f;
        #pragma unroll
        for (int k = 0; k < 16; ++k) s += brecv[10 + k] * peL[tid][k];
        ST[blk*32 + tid] = s;
      }
    }
  } else if (blk < 260) {              // bidir = Wb @ Wb^T (4 blocks)
    float* bidir = ws_f + OFF_BIDIR;
    int q = blk - 256;
    for (int rr = 0; rr < 4; ++rr) {
      int idx = (q*4 + rr) * 256 + tid;
      int i = idx >> 6, j = idx & 63;
      float acc = 0.f;
      for (int e = 0; e < 64; ++e) acc += Wb[i*64+e] * Wb[j*64+e];
      bidir[idx] = acc;
    }
  } else if (blk == 260) {             // WrT, brp (pad16), catx
    for (int r = 0; r < 8; ++r) {
      int idx = r * 256 + tid;
      int d = idx >> 6, e = idx & 63;
      wrt[idx] = (d < 26) ? f2bf(Wrecv[e*26 + d]) : (u16)0;
    }
    if (tid < 16) ws_f[OFF_BRP + tid] = (tid < 10) ? brecv[tid] : 0.f;
    #pragma unroll
    for (int i = 0; i < 4; ++i) {
      int idx = i * 256 + tid;
      int j = idx >> 4, d = idx & 15;
      catx[idx] = (d < 10) ? f2bf(battn[j*10 + d]) : ((d == 10) ? f2bf(1.f) : (u16)0);
    }
  } else {                             // masksumInv[b][i]
    int b = blk - 261;
    int i = tid & 63, q = tid >> 6;
    float s = 0.f;
    for (int t = q*32; t < q*32 + 32; ++t) s += mask[(b*128 + t)*64 + i];
    pm[q][i] = s;
    __syncthreads();
    if (tid < 64)
      (ws_f + OFF_MS)[b*64 + tid] =
          1.0f / (pm[0][tid] + pm[1][tid] + pm[2][tid] + pm[3][tid]);
  }
}

// ---------------- K1: alpha partials (staged) + persist hTg (lane-major) + W1p ----------------
__global__ __launch_bounds__(256)
void k_adj(const float* __restrict__ x, const float* __restrict__ mask,
           const float* __restrict__ Wobs, float* __restrict__ ws_f,
           char* __restrict__ ws_b) {
  __shared__ __align__(16) u16 hA[64][72];
  __shared__ __align__(16) u16 hmA[64][24];

  const int tid = threadIdx.x;
  const int b = blockIdx.y, tc = blockIdx.x;
  const int w = tid >> 6, l = tid & 63, lr = l & 15, lq = l >> 4, kb = lq * 8;
  const int i0 = 16*w + lq*4;
  const u16* wrt  = (const u16*)(ws_b + BOFF_WRT);
  const u16* catx = (const u16*)(ws_b + BOFF_CATX);
  const u16* vv   = (const u16*)(ws_b + BOFF_V);
  const float* brp = ws_f + OFF_BRP;
  const float* ST = ws_f + OFF_ST;
  const float* bidirG = ws_f + OFF_BIDIR;

  const short8 z8 = (short8){0,0,0,0,0,0,0,0};
  const bool lowk = (lq < 2);
  short8 w0 = z8, w1 = z8;
  if (lr < 10) {
    const u16* wr = wrt + lr * 64;
    w0 = *(const short8*)&wr[kb];
    w1 = *(const short8*)&wr[32 + kb];
  }
  short8 bc[4];
  #pragma unroll
  for (int n = 0; n < 4; ++n)
    bc[n] = lowk ? *(const short8*)&catx[(16*n + lr)*16 + lq*8] : z8;
  float4 bv = *(const float4*)&brp[lq*4];
  float bidirR[4][4];
  #pragma unroll
  for (int n = 0; n < 4; ++n)
    #pragma unroll
    for (int reg = 0; reg < 4; ++reg)
      bidirR[n][reg] = bidirG[((i0+reg) << 6) + 16*n + lr];

  f32x4 asum[4];
  #pragma unroll
  for (int n = 0; n < 4; ++n) asum[n] = (f32x4){0.f,0.f,0.f,0.f};

  const int e4 = tid & 15, sg = tid >> 4;

  for (int tt = 0; tt < 8; ++tt) {
    int t = tc * 8 + tt;
    int base = b * 128 + t;
    short8 av0 = z8, av1 = z8;
    if (lr == 10) {
      av0 = *(const short8*)&vv[base*64 + kb];
      av1 = *(const short8*)&vv[base*64 + 32 + kb];
    }
    float st = ST[base];
    { // P0: h build -> hA + lane-major hTg (coalesced 32B/lane)
      float4 mk4 = *(const float4*)&mask[base*64 + sg*4];
      float mks[4] = {mk4.x, mk4.y, mk4.z, mk4.w};
      u16 hv[4][4];
      #pragma unroll
      for (int si = 0; si < 4; ++si) {
        int s = sg*4 + si;
        float4 xv = *(const float4*)&x[base*256 + s*4];
        float xo[4] = {xv.x, xv.y, xv.z, xv.w};
        float ax = 0.f, ay = 0.f, az = 0.f, aw = 0.f;
        #pragma unroll
        for (int o = 0; o < 4; ++o) {
          float4 wv = *(const float4*)&Wobs[(s*4+o)*64 + e4*4];
          ax += xo[o]*wv.x; ay += xo[o]*wv.y; az += xo[o]*wv.z; aw += xo[o]*wv.w;
        }
        float mk = mks[si];
        uint2 p;
        p.x = pk2bf(fmaxf(ax,0.f)*mk, fmaxf(ay,0.f)*mk);
        p.y = pk2bf(fmaxf(az,0.f)*mk, fmaxf(aw,0.f)*mk);
        *(uint2*)&hA[s][e4*4] = p;
        hv[si][0] = (u16)p.x; hv[si][1] = (u16)(p.x >> 16);
        hv[si][2] = (u16)p.y; hv[si][3] = (u16)(p.y >> 16);
      }
      u16* hTg = (u16*)(ws_b + BOFF_HT) + (size_t)base * 4096 + tid * 16;
      uint4 A, B;
      A.x = (u32)hv[0][0] | ((u32)hv[1][0] << 16);
      A.y = (u32)hv[2][0] | ((u32)hv[3][0] << 16);
      A.z = (u32)hv[0][1] | ((u32)hv[1][1] << 16);
      A.w = (u32)hv[2][1] | ((u32)hv[3][1] << 16);
      B.x = (u32)hv[0][2] | ((u32)hv[1][2] << 16);
      B.y = (u32)hv[2][2] | ((u32)hv[3][2] << 16);
      B.z = (u32)hv[0][3] | ((u32)hv[1][3] << 16);
      B.w = (u32)hv[2][3] | ((u32)hv[3][3] << 16);
      *(uint4*)&hTg[0] = A;
      *(uint4*)&hTg[8] = B;
    }
    __syncthreads();
    { // P1: hmx
      short8 a0 = (lr < 10) ? w0 : av0;
      short8 a1 = (lr < 10) ? w1 : av1;
      f32x4 acc = (f32x4){0.f,0.f,0.f,0.f};
      short8 b0 = *(const short8*)&hA[16*w + lr][kb];
      short8 b1 = *(const short8*)&hA[16*w + lr][32 + kb];
      acc = __builtin_amdgcn_mfma_f32_16x16x32_bf16(a0, b0, acc, 0, 0, 0);
      acc = __builtin_amdgcn_mfma_f32_16x16x32_bf16(a1, b1, acc, 0, 0, 0);
      uint2 qq;
      qq.x = pk2bf(acc[0]+bv.x, acc[1]+bv.y);
      qq.y = pk2bf(acc[2]+bv.z, acc[3]+bv.w);
      *(uint2*)&hmA[16*w + lr][lq*4] = qq;
    }
    __syncthreads();
    { // P2: alpha; accumulate asum; write lane-packed w1
      short8 am = lowk ? *(const short8*)&hmA[16*w + lr][lq*8] : z8;
      u32 w1u[8];
      #pragma unroll
      for (int n = 0; n < 4; ++n) {
        f32x4 z = (f32x4){st, st, st, st};
        z = __builtin_amdgcn_mfma_f32_16x16x32_bf16(am, bc[n], z, 0, 0, 0);
        float w1v[4];
        #pragma unroll
        for (int reg = 0; reg < 4; ++reg) {
          float al = fmaxf(z[reg], 0.f);
          asum[n][reg] += al;
          w1v[reg] = al * bidirR[n][reg];
        }
        w1u[2*n]   = pk2bf(w1v[0], w1v[1]);
        w1u[2*n+1] = pk2bf(w1v[2], w1v[3]);
      }
      u16* w1g = (u16*)(ws_b + BOFF_W1) + (size_t)base * 4096 + tid * 16;
      uint4 A, B;
      A.x = w1u[0]; A.y = w1u[1]; A.z = w1u[2]; A.w = w1u[3];
      B.x = w1u[4]; B.y = w1u[5]; B.z = w1u[6]; B.w = w1u[7];
      *(uint4*)&w1g[0] = A;
      *(uint4*)&w1g[8] = B;
    }
    __syncthreads();
  }
  { // staged partials: adjP[tc][b][tid*16 + n*4 + reg]
    float* adjP = (float*)(ws_b + BOFF_ADJP) + (((size_t)tc * 64 + b) << 12) + tid * 16;
    #pragma unroll
    for (int n = 0; n < 4; ++n) {
      float4 A;
      A.x = asum[n][0]; A.y = asum[n][1]; A.z = asum[n][2]; A.w = asum[n][3];
      *(float4*)&adjP[n * 4] = A;
    }
  }
}

// ---------------- K1b: adjS = bf16(sum_tc adjP * msInv) ----------------
__global__ __launch_bounds__(256)
void k_scale(const float* __restrict__ ws_f, char* __restrict__ ws_b) {
  const int b = blockIdx.x, tid = threadIdx.x;
  const int w = tid >> 6, l = tid & 63, lr = l & 15, lq = l >> 4;
  const int i0 = 16*w + lq*4;
  const float* msI = ws_f + OFF_MS + b * 64;
  u16* as_ = (u16*)(ws_b + BOFF_ADJS) + (size_t)b * 4096;

  float S[16];
  #pragma unroll
  for (int k = 0; k < 16; ++k) S[k] = 0.f;
  for (int tc = 0; tc < 16; ++tc) {
    const float4* src = (const float4*)
        ((const float*)(ws_b + BOFF_ADJP) + (((size_t)tc * 64 + b) << 12) + tid * 16);
    #pragma unroll
    for (int n = 0; n < 4; ++n) {
      float4 v = src[n];
      S[n*4+0] += v.x; S[n*4+1] += v.y; S[n*4+2] += v.z; S[n*4+3] += v.w;
    }
  }
  float msr[4];
  #pragma unroll
  for (int reg = 0; reg < 4; ++reg) msr[reg] = msI[i0 + reg];
  #pragma unroll
  for (int n = 0; n < 4; ++n)
    #pragma unroll
    for (int reg = 0; reg < 4; ++reg)
      as_[(i0 + reg) * 64 + 16*n + lr] = f2bf(S[n*4 + reg] * msr[reg]);
}

// ---------------- K2: prop1+prop2 only (loads hTg/W1p/adjS) ----------------
__global__ __launch_bounds__(256, 4)
void k_main(const float* __restrict__ ws_f, const char* __restrict__ ws_b,
            u16* __restrict__ Hh) {
  __shared__ __align__(16) char smem[36864];
  u16 (*h1L)[72] = (u16 (*)[72])(smem);           // h1T [e][i]
  u16 (*hT)[72]  = (u16 (*)[72])(smem + 9216);    // h^T [e][s]
  u16 (*wA)[72]  = (u16 (*)[72])(smem + 18432);   // w1 [i][j]
  u16 (*adjS)[72]= (u16 (*)[72])(smem + 27648);

  const int tid = threadIdx.x;
  const int t = blockIdx.x, b = blockIdx.y;
  const int w = tid >> 6, l = tid & 63, lr = l & 15, lq = l >> 4, kb = lq * 8;
  const int base = b * 128 + t;
  const int i0 = 16*w + lq*4;

  // prefetch everything (96 B/lane, all coalesced)
  const uint4* ag = (const uint4*)(ws_b + BOFF_ADJS + (size_t)b * 8192);
  uint4 g0 = ag[2*tid], g1 = ag[2*tid + 1];
  const uint4* hp = (const uint4*)((const u16*)(ws_b + BOFF_HT) + (size_t)base * 4096);
  uint4 hv0 = hp[2*tid], hv1 = hp[2*tid + 1];
  const uint4* wp = (const uint4*)((const u16*)(ws_b + BOFF_W1) + (size_t)base * 4096);
  uint4 wp0 = wp[2*tid], wp1 = wp[2*tid + 1];

  { // Pa: stage hT (lane-major unpack), wA (unpack scatter), adjS
    const int e4 = tid & 15, sg = tid >> 4;
    uint2 p0; p0.x = hv0.x; p0.y = hv0.y;
    uint2 p1; p1.x = hv0.z; p1.y = hv0.w;
    uint2 p2; p2.x = hv1.x; p2.y = hv1.y;
    uint2 p3; p3.x = hv1.z; p3.y = hv1.w;
    *(uint2*)&hT[e4*4 + 0][sg*4] = p0;
    *(uint2*)&hT[e4*4 + 1][sg*4] = p1;
    *(uint2*)&hT[e4*4 + 2][sg*4] = p2;
    *(uint2*)&hT[e4*4 + 3][sg*4] = p3;
    u32 q[8] = {wp0.x, wp0.y, wp0.z, wp0.w, wp1.x, wp1.y, wp1.z, wp1.w};
    #pragma unroll
    for (int n = 0; n < 4; ++n) {
      int j = 16*n + lr;
      u32 lo = q[2*n], hi = q[2*n+1];
      wA[i0+0][j] = (u16)lo; wA[i0+1][j] = (u16)(lo >> 16);
      wA[i0+2][j] = (u16)hi; wA[i0+3][j] = (u16)(hi >> 16);
    }
    int idx0 = 2*tid, idx1 = 2*tid + 1;
    *(uint4*)&adjS[idx0 >> 3][(idx0 & 7) * 8] = g0;
    *(uint4*)&adjS[idx1 >> 3][(idx1 & 7) * 8] = g1;
  }
  __syncthreads();

  { // Pc: h1 = relu(w1 @ h) -> h1L
    short8 aw0 = *(const short8*)&wA[16*w + lr][kb];
    short8 aw1 = *(const short8*)&wA[16*w + lr][32 + kb];
    #pragma unroll
    for (int n = 0; n < 4; ++n) {
      f32x4 acc = (f32x4){0.f,0.f,0.f,0.f};
      short8 b0 = *(const short8*)&hT[16*n + lr][kb];
      short8 b1 = *(const short8*)&hT[16*n + lr][32 + kb];
      acc = __builtin_amdgcn_mfma_f32_16x16x32_bf16(aw0, b0, acc, 0, 0, 0);
      acc = __builtin_amdgcn_mfma_f32_16x16x32_bf16(aw1, b1, acc, 0, 0, 0);
      int e = 16*n + lr;
      uint2 pp;
      pp.x = pk2bf(fmaxf(acc[0],0.f), fmaxf(acc[1],0.f));
      pp.y = pk2bf(fmaxf(acc[2],0.f), fmaxf(acc[3],0.f));
      *(uint2*)&h1L[e][i0] = pp;
    }
  }
  __syncthreads();

  { // Pd: w2 = w1 (.) adjS; h2 = relu(w2 @ h1) -> Hh
    int row = 16*w + lr;
    union { short8 v; u16 h[8]; u32 u[4]; } uw0, uw1, ud0, ud1, oa, ob;
    uw0.v = *(const short8*)&wA[row][kb];
    uw1.v = *(const short8*)&wA[row][32 + kb];
    ud0.v = *(const short8*)&adjS[row][kb];
    ud1.v = *(const short8*)&adjS[row][32 + kb];
    #pragma unroll
    for (int k = 0; k < 4; ++k) {
      oa.u[k] = pk2bf(bf2f(uw0.h[2*k])*bf2f(ud0.h[2*k]),
                      bf2f(uw0.h[2*k+1])*bf2f(ud0.h[2*k+1]));
      ob.u[k] = pk2bf(bf2f(uw1.h[2*k])*bf2f(ud1.h[2*k]),
                      bf2f(uw1.h[2*k+1])*bf2f(ud1.h[2*k+1]));
    }
    short8 a20 = oa.v, a21 = ob.v;
    size_t obase = ((size_t)b * 64) * 8192 + (size_t)t * 64;
    #pragma unroll
    for (int n = 0; n < 4; ++n) {
      f32x4 acc = (f32x4){0.f,0.f,0.f,0.f};
      short8 b0 = *(const short8*)&h1L[16*n + lr][kb];
      short8 b1 = *(const short8*)&h1L[16*n + lr][32 + kb];
      acc = __builtin_amdgcn_mfma_f32_16x16x32_bf16(a20, b0, acc, 0, 0, 0);
      acc = __builtin_amdgcn_mfma_f32_16x16x32_bf16(a21, b1, acc, 0, 0, 0);
      int e = 16*n + lr;
      u32 p0 = pk2bf(fmaxf(acc[0],0.f), fmaxf(acc[1],0.f));
      u32 p1 = pk2bf(fmaxf(acc[2],0.f), fmaxf(acc[3],0.f));
      Hh[obase + (size_t)(i0+0) * 8192 + e] = (u16)p0;
      Hh[obase + (size_t)(i0+1) * 8192 + e] = (u16)(p0 >> 16);
      Hh[obase + (size_t)(i0+2) * 8192 + e] = (u16)p1;
      Hh[obase + (size_t)(i0+3) * 8192 + e] = (u16)(p1 >> 16);
    }
  }
}

// ---------------- K3: collapsed temporal attention (512 threads, r14 version) ----------------
#define HTP 82

__global__ __launch_bounds__(512)
void k_attn(const char* __restrict__ ws_b, const u16* __restrict__ Hh,
            const float* __restrict__ Wq, const float* __restrict__ bq,
            const float* __restrict__ Wk, const float* __restrict__ bk,
            const float* __restrict__ Ws, const float* __restrict__ bs,
            const float* __restrict__ Wemb, const float* __restrict__ bemb,
            float* __restrict__ out) {
  __shared__ u16 Ht[128][HTP];
  __shared__ u16 peB[128][18];
  __shared__ float wsL[128];
  __shared__ float pA[6][80];
  __shared__ float pK[8][10];
  __shared__ float qvL[80];
  __shared__ float pC[4][128];
  __shared__ float bb[128];
  __shared__ float red[4];
  __shared__ float cstL, sWL;

  const int tid = threadIdx.x;
  const int s = blockIdx.x, b = blockIdx.y;
  const float scale = 0.111803398875f; // 1/sqrt(80)
  const u16* peh = (const u16*)(ws_b + BOFF_PEH);

  const u16* src = Hh + ((size_t)b * 64 + s) * 8192;
  #pragma unroll
  for (int r = 0; r < 2; ++r) {
    int id = r * 512 + tid;
    int tt = id >> 3, c = (id & 7) * 8;
    uint4 q = *(const uint4*)&src[tt * 64 + c];
    u32* dst = (u32*)&Ht[tt][c];
    dst[0] = q.x; dst[1] = q.y; dst[2] = q.z; dst[3] = q.w;
  }
  #pragma unroll
  for (int r = 0; r < 2; ++r) {
    int id = r * 512 + tid;
    u32 pv = ((const u32*)(peh + (size_t)b * 2048))[id];
    *(u32*)&peB[id >> 3][(id & 7) * 2] = pv;
  }
  if (tid < 128) wsL[tid] = Ws[tid];
  __syncthreads();

  if (tid < 480) {
    int d = tid % 80, c = tid / 80;
    int t0 = c * 22, t1 = (t0 + 22 > 128) ? 128 : t0 + 22;
    float a0 = 0.f, a1 = 0.f, a2 = 0.f, a3 = 0.f;
    int t = t0;
    if (d < 64) {
      for (; t + 4 <= t1; t += 4) {
        a0 += wsL[t]   * bf2f(Ht[t][d]);
        a1 += wsL[t+1] * bf2f(Ht[t+1][d]);
        a2 += wsL[t+2] * bf2f(Ht[t+2][d]);
        a3 += wsL[t+3] * bf2f(Ht[t+3][d]);
      }
      for (; t < t1; ++t) a0 += wsL[t] * bf2f(Ht[t][d]);
    } else {
      int k = d - 64;
      for (; t + 4 <= t1; t += 4) {
        a0 += wsL[t]   * bf2f(peB[t][k]);
        a1 += wsL[t+1] * bf2f(peB[t+1][k]);
        a2 += wsL[t+2] * bf2f(peB[t+2][k]);
        a3 += wsL[t+3] * bf2f(peB[t+3][k]);
      }
      for (; t < t1; ++t) a0 += wsL[t] * bf2f(peB[t][k]);
    }
    pA[c][d] = (a0 + a1) + (a2 + a3);
  } else if (tid == 480) {
    float a0 = 0.f, a1 = 0.f, a2 = 0.f, a3 = 0.f;
    for (int t = 0; t < 128; t += 4) {
      a0 += wsL[t]; a1 += wsL[t+1]; a2 += wsL[t+2]; a3 += wsL[t+3];
    }
    sWL = (a0 + a1) + (a2 + a3);
  }
  __syncthreads();

  if (tid < 80) {
    int a = tid % 10, c = tid / 10;
    float a0 = 0.f, a1 = 0.f;
    #pragma unroll
    for (int i = 0; i < 10; i += 2) {
      int d = c * 10 + i;
      float h0 = pA[0][d] + pA[1][d] + pA[2][d] + pA[3][d] + pA[4][d] + pA[5][d];
      float h1 = pA[0][d+1] + pA[1][d+1] + pA[2][d+1] + pA[3][d+1] + pA[4][d+1] + pA[5][d+1];
      a0 += h0 * Wk[d * 10 + a];
      a1 += h1 * Wk[(d+1) * 10 + a];
    }
    pK[c][a] = a0 + a1;
  }
  __syncthreads();

  if (tid <= 80) {
    float kt[10];
    #pragma unroll
    for (int a = 0; a < 10; ++a) {
      float acc = sWL * bk[a];
      #pragma unroll
      for (int c = 0; c < 8; ++c) acc += pK[c][a];
      kt[a] = acc;
    }
    if (tid < 80) {
      float a0 = 0.f, a1 = 0.f;
      #pragma unroll
      for (int a = 0; a < 10; a += 2) {
        a0 += Wq[tid * 10 + a] * kt[a];
        a1 += Wq[tid * 10 + a + 1] * kt[a + 1];
      }
      qvL[tid] = a0 + a1;
    } else {
      float cq = 0.f;
      #pragma unroll
      for (int a = 0; a < 10; ++a) cq += bq[a] * kt[a];
      cstL = scale * cq + bs[0];
    }
  }
  __syncthreads();

  {
    int t = tid & 127, q = tid >> 7;
    float a0 = 0.f, a1 = 0.f, a2 = 0.f, a3 = 0.f;
    const u32* row = (const u32*)&Ht[t][0];
    if (q == 0) {
      #pragma unroll
      for (int i = 0; i < 10; i += 2) {
        u32 p0 = row[i], p1 = row[i+1];
        a0 += bf2f((u16)p0) * qvL[2*i]   + bf2f((u16)(p0 >> 16)) * qvL[2*i+1];
        a1 += bf2f((u16)p1) * qvL[2*i+2] + bf2f((u16)(p1 >> 16)) * qvL[2*i+3];
      }
    } else if (q == 1) {
      #pragma unroll
      for (int i = 10; i < 20; i += 2) {
        u32 p0 = row[i], p1 = row[i+1];
        a0 += bf2f((u16)p0) * qvL[2*i]   + bf2f((u16)(p0 >> 16)) * qvL[2*i+1];
        a1 += bf2f((u16)p1) * qvL[2*i+2] + bf2f((u16)(p1 >> 16)) * qvL[2*i+3];
      }
    } else if (q == 2) {
      #pragma unroll
      for (int i = 20; i < 32; i += 4) {
        u32 p0 = row[i], p1 = row[i+1], p2 = row[i+2], p3 = row[i+3];
        a0 += bf2f((u16)p0) * qvL[2*i]   + bf2f((u16)(p0 >> 16)) * qvL[2*i+1];
        a1 += bf2f((u16)p1) * qvL[2*i+2] + bf2f((u16)(p1 >> 16)) * qvL[2*i+3];
        a2 += bf2f((u16)p2) * qvL[2*i+4] + bf2f((u16)(p2 >> 16)) * qvL[2*i+5];
        a3 += bf2f((u16)p3) * qvL[2*i+6] + bf2f((u16)(p3 >> 16)) * qvL[2*i+7];
      }
    } else {
      #pragma unroll
      for (int k = 0; k < 16; k += 4) {
        a0 += bf2f(peB[t][k])   * qvL[64 + k];
        a1 += bf2f(peB[t][k+1]) * qvL[65 + k];
        a2 += bf2f(peB[t][k+2]) * qvL[66 + k];
        a3 += bf2f(peB[t][k+3]) * qvL[67 + k];
      }
    }
    pC[q][t] = (a0 + a1) + (a2 + a3);
  }
  __syncthreads();

  if (tid < 128) {
    float v = scale * (pC[0][tid] + pC[1][tid] + pC[2][tid] + pC[3][tid]) + cstL;
    bb[tid] = v;
    float mm = v;
    #pragma unroll
    for (int off = 32; off; off >>= 1) mm = fmaxf(mm, __shfl_xor(mm, off));
    if ((tid & 63) == 0) red[tid >> 6] = mm;
  }
  __syncthreads();
  float mx = fmaxf(red[0], red[1]);
  if (tid < 128) {
    float ev = expf(bb[tid] - mx);
    bb[tid] = ev;
    float ss = ev;
    #pragma unroll
    for (int off = 32; off; off >>= 1) ss += __shfl_xor(ss, off);
    if ((tid & 63) == 0) red[2 + (tid >> 6)] = ss;
  }
  __syncthreads();

  if (tid < 480) {
    int d = tid % 80, c = tid / 80;
    int t0 = c * 22, t1 = (t0 + 22 > 128) ? 128 : t0 + 22;
    float a0 = 0.f, a1 = 0.f, a2 = 0.f, a3 = 0.f;
    int t = t0;
    if (d < 64) {
      for (; t + 4 <= t1; t += 4) {
        a0 += bb[t]   * bf2f(Ht[t][d]);
        a1 += bb[t+1] * bf2f(Ht[t+1][d]);
        a2 += bb[t+2] * bf2f(Ht[t+2][d]);
        a3 += bb[t+3] * bf2f(Ht[t+3][d]);
      }
      for (; t < t1; ++t) a0 += bb[t] * bf2f(Ht[t][d]);
    } else {
      int k = d - 64;
      for (; t + 4 <= t1; t += 4) {
        a0 += bb[t]   * bf2f(peB[t][k]);
        a1 += bb[t+1] * bf2f(peB[t+1][k]);
        a2 += bb[t+2] * bf2f(peB[t+2][k]);
        a3 += bb[t+3] * bf2f(peB[t+3][k]);
      }
      for (; t < t1; ++t) a0 += bb[t] * bf2f(peB[t][k]);
    }
    pA[c][d] = (a0 + a1) + (a2 + a3);
  }
  __syncthreads();

  {
    int o = tid & 127, q = tid >> 7;
    int d0 = q * 20;
    float a0 = 0.f, a1 = 0.f, a2 = 0.f, a3 = 0.f;
    #pragma unroll
    for (int i = 0; i < 20; i += 4) {
      int d = d0 + i;
      float h0 = pA[0][d]   + pA[1][d]   + pA[2][d]   + pA[3][d]   + pA[4][d]   + pA[5][d];
      float h1 = pA[0][d+1] + pA[1][d+1] + pA[2][d+1] + pA[3][d+1] + pA[4][d+1] + pA[5][d+1];
      float h2 = pA[0][d+2] + pA[1][d+2] + pA[2][d+2] + pA[3][d+2] + pA[4][d+2] + pA[5][d+2];
      float h3 = pA[0][d+3] + pA[1][d+3] + pA[2][d+3] + pA[3][d+3] + pA[4][d+3] + pA[5][d+3];
      a0 += h0 * Wemb[d * 128 + o];
      a1 += h1 * Wemb[(d+1) * 128 + o];
      a2 += h2 * Wemb[(d+2) * 128 + o];
      a3 += h3 * Wemb[(d+3) * 128 + o];
    }
    pC[q][o] = (a0 + a1) + (a2 + a3);
  }
  __syncthreads();
  if (tid < 128) {
    float rdenom = 1.0f / (red[2] + red[3]);
    out[(((size_t)b * 64 + s) << 7) + tid] =
        bemb[tid] + (pC[0][tid] + pC[1][tid] + pC[2][tid] + pC[3][tid]) * rdenom;
  }
}

extern "C" void kernel_launch(void* const* d_in, const int* in_sizes, int n_in,
                              void* d_out, int out_size, void* d_ws, size_t ws_size,
                              hipStream_t stream) {
  (void)in_sizes; (void)n_in; (void)out_size; (void)ws_size;
  const float* x     = (const float*)d_in[0];
  const float* times = (const float*)d_in[1];
  const float* mask  = (const float*)d_in[2];
  const float* Wobs  = (const float*)d_in[3];
  const float* Wattn = (const float*)d_in[4];
  const float* Wrecv = (const float*)d_in[5];
  const float* brecv = (const float*)d_in[6];
  const float* Wb    = (const float*)d_in[7];
  const float* Wq    = (const float*)d_in[8];
  const float* bq    = (const float*)d_in[9];
  const float* Wk    = (const float*)d_in[10];
  const float* bk    = (const float*)d_in[11];
  const float* Ws    = (const float*)d_in[12];
  const float* bs    = (const float*)d_in[13];
  const float* Wemb  = (const float*)d_in[14];
  const float* bemb  = (const float*)d_in[15];
  float* out = (float*)d_out;
  float* ws_f = (float*)d_ws;
  char* ws_b = (char*)d_ws;
  u16* Hh = (u16*)(ws_b + BOFF_HH);

  k_pre<<<325, 256, 0, stream>>>(times, mask, Wb, Wrecv, brecv, Wattn, ws_f, ws_b);
  k_adj<<<dim3(16, 64), 256, 0, stream>>>(x, mask, Wobs, ws_f, ws_b);
  k_scale<<<64, 256, 0, stream>>>(ws_f, ws_b);
  k_main<<<dim3(128, 64), 256, 0, stream>>>(ws_f, ws_b, Hh);
  k_attn<<<dim3(64, 64), 512, 0, stream>>>(ws_b, Hh, Wq, bq, Wk, bk, Ws, bs, Wemb, bemb, out);
}

// Round 17
// 135.245 us; speedup vs baseline: 1.1589x; 1.0224x over previous
//
#include <hip/hip_runtime.h>
#include <hip/hip_bf16.h>

// Raindrop forward, MI355X. B=64 T=128 S=64 O=4 E=64 P=16 A=10 OUT=128.
//  - temporal attention collapsed: (Q K^T) W_s = Q (W_s^T K)  -> no TxT matrix
//  - alpha decomposition: alpha[i][j] = relu(hm10[i]*battn[j] + h[i].v_t + s_t)
//  - r16 structure: slim k_main (prop-only), lane-major hTg, staged adjP (alias Hh)
//  - r17: k_adj BARRIER-FREE (all LDS deps are warp-local: warp w owns rows
//    16w..16w+15 of hA/hmA through the whole t-loop; DS pipe is in-order per wave)
// ws floats: bidir | masksumInv | brp[16] | sT[8192]
// ws bytes @: WrT 1638464 | catx 1642560 | PEh 1644608 | adjS 1906752 | V 2431040 |
//             W1p 3479616 | hTg 70588480 | Hh 137697344 | adjP=alias(Hh)

typedef unsigned short u16;
typedef unsigned int u32;
typedef __attribute__((ext_vector_type(8))) short short8;
typedef __attribute__((ext_vector_type(4))) float f32x4;

#define OFF_BIDIR 131072
#define OFF_MS    135168
#define OFF_BRP   401408
#define OFF_ST    401424
#define BOFF_WRT  1638464u
#define BOFF_CATX 1642560u
#define BOFF_PEH  1644608u
#define BOFF_ADJS 1906752u
#define BOFF_V    2431040u
#define BOFF_W1   3479616u
#define BOFF_HT   70588480u
#define BOFF_HH   137697344u
#define BOFF_ADJP 137697344u   // alias: dead before Hh is written

__device__ __forceinline__ u16 f2bf(float f){
  __hip_bfloat16 h = __float2bfloat16(f);
  union { __hip_bfloat16 h; u16 u; } v; v.h = h; return v.u;
}
__device__ __forceinline__ u32 pk2bf(float lo, float hi){
  __hip_bfloat162 h = __float22bfloat162_rn(float2{lo, hi});
  union { __hip_bfloat162 h; u32 u; } v; v.h = h; return v.u;
}
__device__ __forceinline__ float bf2f(u16 h){
  union { u32 u; float f; } v; v.u = ((u32)h) << 16; return v.f;
}

// ---------------- K0: peh/v/sT, bidir, WrT/brp/catx, masksumInv ----------------
__global__ void k_pre(const float* __restrict__ times, const float* __restrict__ mask,
                      const float* __restrict__ Wb, const float* __restrict__ Wrecv,
                      const float* __restrict__ brecv, const float* __restrict__ battn,
                      float* __restrict__ ws_f, char* __restrict__ ws_b) {
  __shared__ float peL[32][17];
  __shared__ float wpe[64][17];
  __shared__ float pm[4][64];
  const int blk = blockIdx.x, tid = threadIdx.x;
  u16* wrt  = (u16*)(ws_b + BOFF_WRT);
  u16* catx = (u16*)(ws_b + BOFF_CATX);
  u16* peh  = (u16*)(ws_b + BOFF_PEH);
  u16* vv   = (u16*)(ws_b + BOFF_V);
  float* ST = ws_f + OFF_ST;
  if (blk < 256) {                     // PE (bf16) + v_t + s_t for 32 bt rows
    #pragma unroll
    for (int r = 0; r < 2; ++r) {
      int id = blk * 512 + r * 256 + tid;
      int bt = id >> 4, k = id & 15;
      float tv = times[bt];
      int kk = k & 7;
      float fr = expf(-(float)kk * 1.1512925465f); // ln(1e4)/8
      float ang = tv * fr;
      float v = (k < 8) ? sinf(ang) : cosf(ang);
      peh[id] = f2bf(v);
      peL[r*16 + (tid >> 4)][k] = v;
    }
    #pragma unroll
    for (int q = 0; q < 4; ++q) {
      int idx = q * 256 + tid;
      wpe[idx >> 4][idx & 15] = Wrecv[(idx >> 4)*26 + 10 + (idx & 15)];
    }
    __syncthreads();
    {
      int btl = tid >> 3, e0 = (tid & 7) * 8;
      float acc[8];
      #pragma unroll
      for (int i = 0; i < 8; ++i) acc[i] = 0.f;
      #pragma unroll
      for (int k = 0; k < 16; ++k) {
        float p = peL[btl][k];
        #pragma unroll
        for (int i = 0; i < 8; ++i) acc[i] += wpe[e0 + i][k] * p;
      }
      u32* dst = (u32*)&vv[(blk*32 + btl)*64 + e0];
      #pragma unroll
      for (int p = 0; p < 4; ++p) dst[p] = pk2bf(acc[2*p], acc[2*p+1]);
      if (tid < 32) {
        float s = 0.f;
        #pragma unroll
        for (int k = 0; k < 16; ++k) s += brecv[10 + k] * peL[tid][k];
        ST[blk*32 + tid] = s;
      }
    }
  } else if (blk < 260) {              // bidir = Wb @ Wb^T (4 blocks)
    float* bidir = ws_f + OFF_BIDIR;
    int q = blk - 256;
    for (int rr = 0; rr < 4; ++rr) {
      int idx = (q*4 + rr) * 256 + tid;
      int i = idx >> 6, j = idx & 63;
      float acc = 0.f;
      for (int e = 0; e < 64; ++e) acc += Wb[i*64+e] * Wb[j*64+e];
      bidir[idx] = acc;
    }
  } else if (blk == 260) {             // WrT, brp (pad16), catx
    for (int r = 0; r < 8; ++r) {
      int idx = r * 256 + tid;
      int d = idx >> 6, e = idx & 63;
      wrt[idx] = (d < 26) ? f2bf(Wrecv[e*26 + d]) : (u16)0;
    }
    if (tid < 16) ws_f[OFF_BRP + tid] = (tid < 10) ? brecv[tid] : 0.f;
    #pragma unroll
    for (int i = 0; i < 4; ++i) {
      int idx = i * 256 + tid;
      int j = idx >> 4, d = idx & 15;
      catx[idx] = (d < 10) ? f2bf(battn[j*10 + d]) : ((d == 10) ? f2bf(1.f) : (u16)0);
    }
  } else {                             // masksumInv[b][i]
    int b = blk - 261;
    int i = tid & 63, q = tid >> 6;
    float s = 0.f;
    for (int t = q*32; t < q*32 + 32; ++t) s += mask[(b*128 + t)*64 + i];
    pm[q][i] = s;
    __syncthreads();
    if (tid < 64)
      (ws_f + OFF_MS)[b*64 + tid] =
          1.0f / (pm[0][tid] + pm[1][tid] + pm[2][tid] + pm[3][tid]);
  }
}

// ---------------- K1: alpha partials + persist hTg/W1p — BARRIER-FREE ----------------
__global__ __launch_bounds__(256)
void k_adj(const float* __restrict__ x, const float* __restrict__ mask,
           const float* __restrict__ Wobs, float* __restrict__ ws_f,
           char* __restrict__ ws_b) {
  // warp w exclusively owns rows [16w,16w+16) of hA and hmA -> no __syncthreads
  __shared__ __align__(16) u16 hA[64][72];
  __shared__ __align__(16) u16 hmA[64][24];

  const int tid = threadIdx.x;
  const int b = blockIdx.y, tc = blockIdx.x;
  const int w = tid >> 6, l = tid & 63, lr = l & 15, lq = l >> 4, kb = lq * 8;
  const int i0 = 16*w + lq*4;
  const u16* wrt  = (const u16*)(ws_b + BOFF_WRT);
  const u16* catx = (const u16*)(ws_b + BOFF_CATX);
  const u16* vv   = (const u16*)(ws_b + BOFF_V);
  const float* brp = ws_f + OFF_BRP;
  const float* ST = ws_f + OFF_ST;
  const float* bidirG = ws_f + OFF_BIDIR;

  const short8 z8 = (short8){0,0,0,0,0,0,0,0};
  const bool lowk = (lq < 2);
  short8 w0 = z8, w1 = z8;
  if (lr < 10) {
    const u16* wr = wrt + lr * 64;
    w0 = *(const short8*)&wr[kb];
    w1 = *(const short8*)&wr[32 + kb];
  }
  short8 bc[4];
  #pragma unroll
  for (int n = 0; n < 4; ++n)
    bc[n] = lowk ? *(const short8*)&catx[(16*n + lr)*16 + lq*8] : z8;
  float4 bv = *(const float4*)&brp[lq*4];
  float bidirR[4][4];
  #pragma unroll
  for (int n = 0; n < 4; ++n)
    #pragma unroll
    for (int reg = 0; reg < 4; ++reg)
      bidirR[n][reg] = bidirG[((i0+reg) << 6) + 16*n + lr];

  f32x4 asum[4];
  #pragma unroll
  for (int n = 0; n < 4; ++n) asum[n] = (f32x4){0.f,0.f,0.f,0.f};

  const int e4 = tid & 15, sg = tid >> 4;   // sg in [4w,4w+4): warp-local s rows

  for (int tt = 0; tt < 8; ++tt) {
    int t = tc * 8 + tt;
    int base = b * 128 + t;
    short8 av0 = z8, av1 = z8;
    if (lr == 10) {
      av0 = *(const short8*)&vv[base*64 + kb];
      av1 = *(const short8*)&vv[base*64 + 32 + kb];
    }
    float st = ST[base];
    { // P0: h build -> hA (warp-local rows) + lane-major hTg
      float4 mk4 = *(const float4*)&mask[base*64 + sg*4];
      float mks[4] = {mk4.x, mk4.y, mk4.z, mk4.w};
      u16 hv[4][4];
      #pragma unroll
      for (int si = 0; si < 4; ++si) {
        int s = sg*4 + si;
        float4 xv = *(const float4*)&x[base*256 + s*4];
        float xo[4] = {xv.x, xv.y, xv.z, xv.w};
        float ax = 0.f, ay = 0.f, az = 0.f, aw = 0.f;
        #pragma unroll
        for (int o = 0; o < 4; ++o) {
          float4 wv = *(const float4*)&Wobs[(s*4+o)*64 + e4*4];
          ax += xo[o]*wv.x; ay += xo[o]*wv.y; az += xo[o]*wv.z; aw += xo[o]*wv.w;
        }
        float mk = mks[si];
        uint2 p;
        p.x = pk2bf(fmaxf(ax,0.f)*mk, fmaxf(ay,0.f)*mk);
        p.y = pk2bf(fmaxf(az,0.f)*mk, fmaxf(aw,0.f)*mk);
        *(uint2*)&hA[s][e4*4] = p;
        hv[si][0] = (u16)p.x; hv[si][1] = (u16)(p.x >> 16);
        hv[si][2] = (u16)p.y; hv[si][3] = (u16)(p.y >> 16);
      }
      u16* hTg = (u16*)(ws_b + BOFF_HT) + (size_t)base * 4096 + tid * 16;
      uint4 A, B;
      A.x = (u32)hv[0][0] | ((u32)hv[1][0] << 16);
      A.y = (u32)hv[2][0] | ((u32)hv[3][0] << 16);
      A.z = (u32)hv[0][1] | ((u32)hv[1][1] << 16);
      A.w = (u32)hv[2][1] | ((u32)hv[3][1] << 16);
      B.x = (u32)hv[0][2] | ((u32)hv[1][2] << 16);
      B.y = (u32)hv[2][2] | ((u32)hv[3][2] << 16);
      B.z = (u32)hv[0][3] | ((u32)hv[1][3] << 16);
      B.w = (u32)hv[2][3] | ((u32)hv[3][3] << 16);
      *(uint4*)&hTg[0] = A;
      *(uint4*)&hTg[8] = B;
    }
    { // P1: hmx (reads/writes warp-local rows only)
      short8 a0 = (lr < 10) ? w0 : av0;
      short8 a1 = (lr < 10) ? w1 : av1;
      f32x4 acc = (f32x4){0.f,0.f,0.f,0.f};
      short8 b0 = *(const short8*)&hA[16*w + lr][kb];
      short8 b1 = *(const short8*)&hA[16*w + lr][32 + kb];
      acc = __builtin_amdgcn_mfma_f32_16x16x32_bf16(a0, b0, acc, 0, 0, 0);
      acc = __builtin_amdgcn_mfma_f32_16x16x32_bf16(a1, b1, acc, 0, 0, 0);
      uint2 qq;
      qq.x = pk2bf(acc[0]+bv.x, acc[1]+bv.y);
      qq.y = pk2bf(acc[2]+bv.z, acc[3]+bv.w);
      *(uint2*)&hmA[16*w + lr][lq*4] = qq;
    }
    { // P2: alpha; accumulate asum; write lane-packed w1
      short8 am = lowk ? *(const short8*)&hmA[16*w + lr][lq*8] : z8;
      u32 w1u[8];
      #pragma unroll
      for (int n = 0; n < 4; ++n) {
        f32x4 z = (f32x4){st, st, st, st};
        z = __builtin_amdgcn_mfma_f32_16x16x32_bf16(am, bc[n], z, 0, 0, 0);
        float w1v[4];
        #pragma unroll
        for (int reg = 0; reg < 4; ++reg) {
          float al = fmaxf(z[reg], 0.f);
          asum[n][reg] += al;
          w1v[reg] = al * bidirR[n][reg];
        }
        w1u[2*n]   = pk2bf(w1v[0], w1v[1]);
        w1u[2*n+1] = pk2bf(w1v[2], w1v[3]);
      }
      u16* w1g = (u16*)(ws_b + BOFF_W1) + (size_t)base * 4096 + tid * 16;
      uint4 A, B;
      A.x = w1u[0]; A.y = w1u[1]; A.z = w1u[2]; A.w = w1u[3];
      B.x = w1u[4]; B.y = w1u[5]; B.z = w1u[6]; B.w = w1u[7];
      *(uint4*)&w1g[0] = A;
      *(uint4*)&w1g[8] = B;
    }
  }
  { // staged partials: adjP[tc][b][tid*16 + n*4 + reg]
    float* adjP = (float*)(ws_b + BOFF_ADJP) + (((size_t)tc * 64 + b) << 12) + tid * 16;
    #pragma unroll
    for (int n = 0; n < 4; ++n) {
      float4 A;
      A.x = asum[n][0]; A.y = asum[n][1]; A.z = asum[n][2]; A.w = asum[n][3];
      *(float4*)&adjP[n * 4] = A;
    }
  }
}

// ---------------- K1b: adjS = bf16(sum_tc adjP * msInv) ----------------
__global__ __launch_bounds__(256)
void k_scale(const float* __restrict__ ws_f, char* __restrict__ ws_b) {
  const int b = blockIdx.x, tid = threadIdx.x;
  const int w = tid >> 6, l = tid & 63, lr = l & 15, lq = l >> 4;
  const int i0 = 16*w + lq*4;
  const float* msI = ws_f + OFF_MS + b * 64;
  u16* as_ = (u16*)(ws_b + BOFF_ADJS) + (size_t)b * 4096;

  float S[16];
  #pragma unroll
  for (int k = 0; k < 16; ++k) S[k] = 0.f;
  for (int tc = 0; tc < 16; ++tc) {
    const float4* src = (const float4*)
        ((const float*)(ws_b + BOFF_ADJP) + (((size_t)tc * 64 + b) << 12) + tid * 16);
    #pragma unroll
    for (int n = 0; n < 4; ++n) {
      float4 v = src[n];
      S[n*4+0] += v.x; S[n*4+1] += v.y; S[n*4+2] += v.z; S[n*4+3] += v.w;
    }
  }
  float msr[4];
  #pragma unroll
  for (int reg = 0; reg < 4; ++reg) msr[reg] = msI[i0 + reg];
  #pragma unroll
  for (int n = 0; n < 4; ++n)
    #pragma unroll
    for (int reg = 0; reg < 4; ++reg)
      as_[(i0 + reg) * 64 + 16*n + lr] = f2bf(S[n*4 + reg] * msr[reg]);
}

// ---------------- K2: prop1+prop2 only (loads hTg/W1p/adjS) ----------------
__global__ __launch_bounds__(256, 4)
void k_main(const float* __restrict__ ws_f, const char* __restrict__ ws_b,
            u16* __restrict__ Hh) {
  __shared__ __align__(16) char smem[36864];
  u16 (*h1L)[72] = (u16 (*)[72])(smem);           // h1T [e][i]
  u16 (*hT)[72]  = (u16 (*)[72])(smem + 9216);    // h^T [e][s]
  u16 (*wA)[72]  = (u16 (*)[72])(smem + 18432);   // w1 [i][j]
  u16 (*adjS)[72]= (u16 (*)[72])(smem + 27648);

  const int tid = threadIdx.x;
  const int t = blockIdx.x, b = blockIdx.y;
  const int w = tid >> 6, l = tid & 63, lr = l & 15, lq = l >> 4, kb = lq * 8;
  const int base = b * 128 + t;
  const int i0 = 16*w + lq*4;

  // prefetch everything (96 B/lane, all coalesced)
  const uint4* ag = (const uint4*)(ws_b + BOFF_ADJS + (size_t)b * 8192);
  uint4 g0 = ag[2*tid], g1 = ag[2*tid + 1];
  const uint4* hp = (const uint4*)((const u16*)(ws_b + BOFF_HT) + (size_t)base * 4096);
  uint4 hv0 = hp[2*tid], hv1 = hp[2*tid + 1];
  const uint4* wp = (const uint4*)((const u16*)(ws_b + BOFF_W1) + (size_t)base * 4096);
  uint4 wp0 = wp[2*tid], wp1 = wp[2*tid + 1];

  { // Pa: stage hT (lane-major unpack), wA (unpack scatter), adjS
    const int e4 = tid & 15, sg = tid >> 4;
    uint2 p0; p0.x = hv0.x; p0.y = hv0.y;
    uint2 p1; p1.x = hv0.z; p1.y = hv0.w;
    uint2 p2; p2.x = hv1.x; p2.y = hv1.y;
    uint2 p3; p3.x = hv1.z; p3.y = hv1.w;
    *(uint2*)&hT[e4*4 + 0][sg*4] = p0;
    *(uint2*)&hT[e4*4 + 1][sg*4] = p1;
    *(uint2*)&hT[e4*4 + 2][sg*4] = p2;
    *(uint2*)&hT[e4*4 + 3][sg*4] = p3;
    u32 q[8] = {wp0.x, wp0.y, wp0.z, wp0.w, wp1.x, wp1.y, wp1.z, wp1.w};
    #pragma unroll
    for (int n = 0; n < 4; ++n) {
      int j = 16*n + lr;
      u32 lo = q[2*n], hi = q[2*n+1];
      wA[i0+0][j] = (u16)lo; wA[i0+1][j] = (u16)(lo >> 16);
      wA[i0+2][j] = (u16)hi; wA[i0+3][j] = (u16)(hi >> 16);
    }
    int idx0 = 2*tid, idx1 = 2*tid + 1;
    *(uint4*)&adjS[idx0 >> 3][(idx0 & 7) * 8] = g0;
    *(uint4*)&adjS[idx1 >> 3][(idx1 & 7) * 8] = g1;
  }
  __syncthreads();

  { // Pc: h1 = relu(w1 @ h) -> h1L
    short8 aw0 = *(const short8*)&wA[16*w + lr][kb];
    short8 aw1 = *(const short8*)&wA[16*w + lr][32 + kb];
    #pragma unroll
    for (int n = 0; n < 4; ++n) {
      f32x4 acc = (f32x4){0.f,0.f,0.f,0.f};
      short8 b0 = *(const short8*)&hT[16*n + lr][kb];
      short8 b1 = *(const short8*)&hT[16*n + lr][32 + kb];
      acc = __builtin_amdgcn_mfma_f32_16x16x32_bf16(aw0, b0, acc, 0, 0, 0);
      acc = __builtin_amdgcn_mfma_f32_16x16x32_bf16(aw1, b1, acc, 0, 0, 0);
      int e = 16*n + lr;
      uint2 pp;
      pp.x = pk2bf(fmaxf(acc[0],0.f), fmaxf(acc[1],0.f));
      pp.y = pk2bf(fmaxf(acc[2],0.f), fmaxf(acc[3],0.f));
      *(uint2*)&h1L[e][i0] = pp;
    }
  }
  __syncthreads();

  { // Pd: w2 = w1 (.) adjS; h2 = relu(w2 @ h1) -> Hh
    int row = 16*w + lr;
    union { short8 v; u16 h[8]; u32 u[4]; } uw0, uw1, ud0, ud1, oa, ob;
    uw0.v = *(const short8*)&wA[row][kb];
    uw1.v = *(const short8*)&wA[row][32 + kb];
    ud0.v = *(const short8*)&adjS[row][kb];
    ud1.v = *(const short8*)&adjS[row][32 + kb];
    #pragma unroll
    for (int k = 0; k < 4; ++k) {
      oa.u[k] = pk2bf(bf2f(uw0.h[2*k])*bf2f(ud0.h[2*k]),
                      bf2f(uw0.h[2*k+1])*bf2f(ud0.h[2*k+1]));
      ob.u[k] = pk2bf(bf2f(uw1.h[2*k])*bf2f(ud1.h[2*k]),
                      bf2f(uw1.h[2*k+1])*bf2f(ud1.h[2*k+1]));
    }
    short8 a20 = oa.v, a21 = ob.v;
    size_t obase = ((size_t)b * 64) * 8192 + (size_t)t * 64;
    #pragma unroll
    for (int n = 0; n < 4; ++n) {
      f32x4 acc = (f32x4){0.f,0.f,0.f,0.f};
      short8 b0 = *(const short8*)&h1L[16*n + lr][kb];
      short8 b1 = *(const short8*)&h1L[16*n + lr][32 + kb];
      acc = __builtin_amdgcn_mfma_f32_16x16x32_bf16(a20, b0, acc, 0, 0, 0);
      acc = __builtin_amdgcn_mfma_f32_16x16x32_bf16(a21, b1, acc, 0, 0, 0);
      int e = 16*n + lr;
      u32 p0 = pk2bf(fmaxf(acc[0],0.f), fmaxf(acc[1],0.f));
      u32 p1 = pk2bf(fmaxf(acc[2],0.f), fmaxf(acc[3],0.f));
      Hh[obase + (size_t)(i0+0) * 8192 + e] = (u16)p0;
      Hh[obase + (size_t)(i0+1) * 8192 + e] = (u16)(p0 >> 16);
      Hh[obase + (size_t)(i0+2) * 8192 + e] = (u16)p1;
      Hh[obase + (size_t)(i0+3) * 8192 + e] = (u16)(p1 >> 16);
    }
  }
}

// ---------------- K3: collapsed temporal attention (512 threads) ----------------
#define HTP 82

__global__ __launch_bounds__(512)
void k_attn(const char* __restrict__ ws_b, const u16* __restrict__ Hh,
            const float* __restrict__ Wq, const float* __restrict__ bq,
            const float* __restrict__ Wk, const float* __restrict__ bk,
            const float* __restrict__ Ws, const float* __restrict__ bs,
            const float* __restrict__ Wemb, const float* __restrict__ bemb,
            float* __restrict__ out) {
  __shared__ u16 Ht[128][HTP];
  __shared__ u16 peB[128][18];
  __shared__ float wsL[128];
  __shared__ float pA[6][80];
  __shared__ float pK[8][10];
  __shared__ float qvL[80];
  __shared__ float pC[4][128];
  __shared__ float bb[128];
  __shared__ float red[4];
  __shared__ float cstL, sWL;

  const int tid = threadIdx.x;
  const int s = blockIdx.x, b = blockIdx.y;
  const float scale = 0.111803398875f; // 1/sqrt(80)
  const u16* peh = (const u16*)(ws_b + BOFF_PEH);

  const u16* src = Hh + ((size_t)b * 64 + s) * 8192;
  #pragma unroll
  for (int r = 0; r < 2; ++r) {
    int id = r * 512 + tid;
    int tt = id >> 3, c = (id & 7) * 8;
    uint4 q = *(const uint4*)&src[tt * 64 + c];
    u32* dst = (u32*)&Ht[tt][c];
    dst[0] = q.x; dst[1] = q.y; dst[2] = q.z; dst[3] = q.w;
  }
  #pragma unroll
  for (int r = 0; r < 2; ++r) {
    int id = r * 512 + tid;
    u32 pv = ((const u32*)(peh + (size_t)b * 2048))[id];
    *(u32*)&peB[id >> 3][(id & 7) * 2] = pv;
  }
  if (tid < 128) wsL[tid] = Ws[tid];
  __syncthreads();

  if (tid < 480) {
    int d = tid % 80, c = tid / 80;
    int t0 = c * 22, t1 = (t0 + 22 > 128) ? 128 : t0 + 22;
    float a0 = 0.f, a1 = 0.f, a2 = 0.f, a3 = 0.f;
    int t = t0;
    if (d < 64) {
      for (; t + 4 <= t1; t += 4) {
        a0 += wsL[t]   * bf2f(Ht[t][d]);
        a1 += wsL[t+1] * bf2f(Ht[t+1][d]);
        a2 += wsL[t+2] * bf2f(Ht[t+2][d]);
        a3 += wsL[t+3] * bf2f(Ht[t+3][d]);
      }
      for (; t < t1; ++t) a0 += wsL[t] * bf2f(Ht[t][d]);
    } else {
      int k = d - 64;
      for (; t + 4 <= t1; t += 4) {
        a0 += wsL[t]   * bf2f(peB[t][k]);
        a1 += wsL[t+1] * bf2f(peB[t+1][k]);
        a2 += wsL[t+2] * bf2f(peB[t+2][k]);
        a3 += wsL[t+3] * bf2f(peB[t+3][k]);
      }
      for (; t < t1; ++t) a0 += wsL[t] * bf2f(peB[t][k]);
    }
    pA[c][d] = (a0 + a1) + (a2 + a3);
  } else if (tid == 480) {
    float a0 = 0.f, a1 = 0.f, a2 = 0.f, a3 = 0.f;
    for (int t = 0; t < 128; t += 4) {
      a0 += wsL[t]; a1 += wsL[t+1]; a2 += wsL[t+2]; a3 += wsL[t+3];
    }
    sWL = (a0 + a1) + (a2 + a3);
  }
  __syncthreads();

  if (tid < 80) {
    int a = tid % 10, c = tid / 10;
    float a0 = 0.f, a1 = 0.f;
    #pragma unroll
    for (int i = 0; i < 10; i += 2) {
      int d = c * 10 + i;
      float h0 = pA[0][d] + pA[1][d] + pA[2][d] + pA[3][d] + pA[4][d] + pA[5][d];
      float h1 = pA[0][d+1] + pA[1][d+1] + pA[2][d+1] + pA[3][d+1] + pA[4][d+1] + pA[5][d+1];
      a0 += h0 * Wk[d * 10 + a];
      a1 += h1 * Wk[(d+1) * 10 + a];
    }
    pK[c][a] = a0 + a1;
  }
  __syncthreads();

  if (tid <= 80) {
    float kt[10];
    #pragma unroll
    for (int a = 0; a < 10; ++a) {
      float acc = sWL * bk[a];
      #pragma unroll
      for (int c = 0; c < 8; ++c) acc += pK[c][a];
      kt[a] = acc;
    }
    if (tid < 80) {
      float a0 = 0.f, a1 = 0.f;
      #pragma unroll
      for (int a = 0; a < 10; a += 2) {
        a0 += Wq[tid * 10 + a] * kt[a];
        a1 += Wq[tid * 10 + a + 1] * kt[a + 1];
      }
      qvL[tid] = a0 + a1;
    } else {
      float cq = 0.f;
      #pragma unroll
      for (int a = 0; a < 10; ++a) cq += bq[a] * kt[a];
      cstL = scale * cq + bs[0];
    }
  }
  __syncthreads();

  {
    int t = tid & 127, q = tid >> 7;
    float a0 = 0.f, a1 = 0.f, a2 = 0.f, a3 = 0.f;
    const u32* row = (const u32*)&Ht[t][0];
    if (q == 0) {
      #pragma unroll
      for (int i = 0; i < 10; i += 2) {
        u32 p0 = row[i], p1 = row[i+1];
        a0 += bf2f((u16)p0) * qvL[2*i]   + bf2f((u16)(p0 >> 16)) * qvL[2*i+1];
        a1 += bf2f((u16)p1) * qvL[2*i+2] + bf2f((u16)(p1 >> 16)) * qvL[2*i+3];
      }
    } else if (q == 1) {
      #pragma unroll
      for (int i = 10; i < 20; i += 2) {
        u32 p0 = row[i], p1 = row[i+1];
        a0 += bf2f((u16)p0) * qvL[2*i]   + bf2f((u16)(p0 >> 16)) * qvL[2*i+1];
        a1 += bf2f((u16)p1) * qvL[2*i+2] + bf2f((u16)(p1 >> 16)) * qvL[2*i+3];
      }
    } else if (q == 2) {
      #pragma unroll
      for (int i = 20; i < 32; i += 4) {
        u32 p0 = row[i], p1 = row[i+1], p2 = row[i+2], p3 = row[i+3];
        a0 += bf2f((u16)p0) * qvL[2*i]   + bf2f((u16)(p0 >> 16)) * qvL[2*i+1];
        a1 += bf2f((u16)p1) * qvL[2*i+2] + bf2f((u16)(p1 >> 16)) * qvL[2*i+3];
        a2 += bf2f((u16)p2) * qvL[2*i+4] + bf2f((u16)(p2 >> 16)) * qvL[2*i+5];
        a3 += bf2f((u16)p3) * qvL[2*i+6] + bf2f((u16)(p3 >> 16)) * qvL[2*i+7];
      }
    } else {
      #pragma unroll
      for (int k = 0; k < 16; k += 4) {
        a0 += bf2f(peB[t][k])   * qvL[64 + k];
        a1 += bf2f(peB[t][k+1]) * qvL[65 + k];
        a2 += bf2f(peB[t][k+2]) * qvL[66 + k];
        a3 += bf2f(peB[t][k+3]) * qvL[67 + k];
      }
    }
    pC[q][t] = (a0 + a1) + (a2 + a3);
  }
  __syncthreads();

  if (tid < 128) {
    float v = scale * (pC[0][tid] + pC[1][tid] + pC[2][tid] + pC[3][tid]) + cstL;
    bb[tid] = v;
    float mm = v;
    #pragma unroll
    for (int off = 32; off; off >>= 1) mm = fmaxf(mm, __shfl_xor(mm, off));
    if ((tid & 63) == 0) red[tid >> 6] = mm;
  }
  __syncthreads();
  float mx = fmaxf(red[0], red[1]);
  if (tid < 128) {
    float ev = expf(bb[tid] - mx);
    bb[tid] = ev;
    float ss = ev;
    #pragma unroll
    for (int off = 32; off; off >>= 1) ss += __shfl_xor(ss, off);
    if ((tid & 63) == 0) red[2 + (tid >> 6)] = ss;
  }
  __syncthreads();

  if (tid < 480) {
    int d = tid % 80, c = tid / 80;
    int t0 = c * 22, t1 = (t0 + 22 > 128) ? 128 : t0 + 22;
    float a0 = 0.f, a1 = 0.f, a2 = 0.f, a3 = 0.f;
    int t = t0;
    if (d < 64) {
      for (; t + 4 <= t1; t += 4) {
        a0 += bb[t]   * bf2f(Ht[t][d]);
        a1 += bb[t+1] * bf2f(Ht[t+1][d]);
        a2 += bb[t+2] * bf2f(Ht[t+2][d]);
        a3 += bb[t+3] * bf2f(Ht[t+3][d]);
      }
      for (; t < t1; ++t) a0 += bb[t] * bf2f(Ht[t][d]);
    } else {
      int k = d - 64;
      for (; t + 4 <= t1; t += 4) {
        a0 += bb[t]   * bf2f(peB[t][k]);
        a1 += bb[t+1] * bf2f(peB[t+1][k]);
        a2 += bb[t+2] * bf2f(peB[t+2][k]);
        a3 += bb[t+3] * bf2f(peB[t+3][k]);
      }
      for (; t < t1; ++t) a0 += bb[t] * bf2f(peB[t][k]);
    }
    pA[c][d] = (a0 + a1) + (a2 + a3);
  }
  __syncthreads();

  {
    int o = tid & 127, q = tid >> 7;
    int d0 = q * 20;
    float a0 = 0.f, a1 = 0.f, a2 = 0.f, a3 = 0.f;
    #pragma unroll
    for (int i = 0; i < 20; i += 4) {
      int d = d0 + i;
      float h0 = pA[0][d]   + pA[1][d]   + pA[2][d]   + pA[3][d]   + pA[4][d]   + pA[5][d];
      float h1 = pA[0][d+1] + pA[1][d+1] + pA[2][d+1] + pA[3][d+1] + pA[4][d+1] + pA[5][d+1];
      float h2 = pA[0][d+2] + pA[1][d+2] + pA[2][d+2] + pA[3][d+2] + pA[4][d+2] + pA[5][d+2];
      float h3 = pA[0][d+3] + pA[1][d+3] + pA[2][d+3] + pA[3][d+3] + pA[4][d+3] + pA[5][d+3];
      a0 += h0 * Wemb[d * 128 + o];
      a1 += h1 * Wemb[(d+1) * 128 + o];
      a2 += h2 * Wemb[(d+2) * 128 + o];
      a3 += h3 * Wemb[(d+3) * 128 + o];
    }
    pC[q][o] = (a0 + a1) + (a2 + a3);
  }
  __syncthreads();
  if (tid < 128) {
    float rdenom = 1.0f / (red[2] + red[3]);
    out[(((size_t)b * 64 + s) << 7) + tid] =
        bemb[tid] + (pC[0][tid] + pC[1][tid] + pC[2][tid] + pC[3][tid]) * rdenom;
  }
}

extern "C" void kernel_launch(void* const* d_in, const int* in_sizes, int n_in,
                              void* d_out, int out_size, void* d_ws, size_t ws_size,
                              hipStream_t stream) {
  (void)in_sizes; (void)n_in; (void)out_size; (void)ws_size;
  const float* x     = (const float*)d_in[0];
  const float* times = (const float*)d_in[1];
  const float* mask  = (const float*)d_in[2];
  const float* Wobs  = (const float*)d_in[3];
  const float* Wattn = (const float*)d_in[4];
  const float* Wrecv = (const float*)d_in[5];
  const float* brecv = (const float*)d_in[6];
  const float* Wb    = (const float*)d_in[7];
  const float* Wq    = (const float*)d_in[8];
  const float* bq    = (const float*)d_in[9];
  const float* Wk    = (const float*)d_in[10];
  const float* bk    = (const float*)d_in[11];
  const float* Ws    = (const float*)d_in[12];
  const float* bs    = (const float*)d_in[13];
  const float* Wemb  = (const float*)d_in[14];
  const float* bemb  = (const float*)d_in[15];
  float* out = (float*)d_out;
  float* ws_f = (float*)d_ws;
  char* ws_b = (char*)d_ws;
  u16* Hh = (u16*)(ws_b + BOFF_HH);

  k_pre<<<325, 256, 0, stream>>>(times, mask, Wb, Wrecv, brecv, Wattn, ws_f, ws_b);
  k_adj<<<dim3(16, 64), 256, 0, stream>>>(x, mask, Wobs, ws_f, ws_b);
  k_scale<<<64, 256, 0, stream>>>(ws_f, ws_b);
  k_main<<<dim3(128, 64), 256, 0, stream>>>(ws_f, ws_b, Hh);
  k_attn<<<dim3(64, 64), 512, 0, stream>>>(ws_b, Hh, Wq, bq, Wk, bk, Ws, bs, Wemb, bemb, out);
}

// Round 19
// 135.021 us; speedup vs baseline: 1.1609x; 1.0017x over previous
//
#include <hip/hip_runtime.h>
#include <hip/hip_bf16.h>

// Raindrop forward, MI355X. B=64 T=128 S=64 O=4 E=64 P=16 A=10 OUT=128.
//  - temporal attention collapsed: (Q K^T) W_s = Q (W_s^T K)  -> no TxT matrix
//  - alpha decomposition: alpha[i][j] = relu(hm10[i]*battn[j] + h[i].v_t + s_t)
//  - r17 structure: slim k_main, lane-major hTg, staged adjP (alias Hh), barrier-free k_adj
//  - r19: r18's k_attn (f32 Ht + wave-uniform A/E) with phase-C range FIXED:
//    H covered by exactly 16 float4 iters (q0:0-5, q1:6-11, q2:12-15), q3 = PE
// ws floats: bidir | masksumInv | brp[16] | sT[8192]
// ws bytes @: WrT 1638464 | catx 1642560 | PEh 1644608 | adjS 1906752 | V 2431040 |
//             W1p 3479616 | hTg 70588480 | Hh 137697344 | adjP=alias(Hh)

typedef unsigned short u16;
typedef unsigned int u32;
typedef __attribute__((ext_vector_type(8))) short short8;
typedef __attribute__((ext_vector_type(4))) float f32x4;

#define OFF_BIDIR 131072
#define OFF_MS    135168
#define OFF_BRP   401408
#define OFF_ST    401424
#define BOFF_WRT  1638464u
#define BOFF_CATX 1642560u
#define BOFF_PEH  1644608u
#define BOFF_ADJS 1906752u
#define BOFF_V    2431040u
#define BOFF_W1   3479616u
#define BOFF_HT   70588480u
#define BOFF_HH   137697344u
#define BOFF_ADJP 137697344u   // alias: dead before Hh is written

__device__ __forceinline__ u16 f2bf(float f){
  __hip_bfloat16 h = __float2bfloat16(f);
  union { __hip_bfloat16 h; u16 u; } v; v.h = h; return v.u;
}
__device__ __forceinline__ u32 pk2bf(float lo, float hi){
  __hip_bfloat162 h = __float22bfloat162_rn(float2{lo, hi});
  union { __hip_bfloat162 h; u32 u; } v; v.h = h; return v.u;
}
__device__ __forceinline__ float bf2f(u16 h){
  union { u32 u; float f; } v; v.u = ((u32)h) << 16; return v.f;
}

// ---------------- K0: peh/v/sT, bidir, WrT/brp/catx, masksumInv ----------------
__global__ void k_pre(const float* __restrict__ times, const float* __restrict__ mask,
                      const float* __restrict__ Wb, const float* __restrict__ Wrecv,
                      const float* __restrict__ brecv, const float* __restrict__ battn,
                      float* __restrict__ ws_f, char* __restrict__ ws_b) {
  __shared__ float peL[32][17];
  __shared__ float wpe[64][17];
  __shared__ float pm[4][64];
  const int blk = blockIdx.x, tid = threadIdx.x;
  u16* wrt  = (u16*)(ws_b + BOFF_WRT);
  u16* catx = (u16*)(ws_b + BOFF_CATX);
  u16* peh  = (u16*)(ws_b + BOFF_PEH);
  u16* vv   = (u16*)(ws_b + BOFF_V);
  float* ST = ws_f + OFF_ST;
  if (blk < 256) {                     // PE (bf16) + v_t + s_t for 32 bt rows
    #pragma unroll
    for (int r = 0; r < 2; ++r) {
      int id = blk * 512 + r * 256 + tid;
      int bt = id >> 4, k = id & 15;
      float tv = times[bt];
      int kk = k & 7;
      float fr = expf(-(float)kk * 1.1512925465f); // ln(1e4)/8
      float ang = tv * fr;
      float v = (k < 8) ? sinf(ang) : cosf(ang);
      peh[id] = f2bf(v);
      peL[r*16 + (tid >> 4)][k] = v;
    }
    #pragma unroll
    for (int q = 0; q < 4; ++q) {
      int idx = q * 256 + tid;
      wpe[idx >> 4][idx & 15] = Wrecv[(idx >> 4)*26 + 10 + (idx & 15)];
    }
    __syncthreads();
    {
      int btl = tid >> 3, e0 = (tid & 7) * 8;
      float acc[8];
      #pragma unroll
      for (int i = 0; i < 8; ++i) acc[i] = 0.f;
      #pragma unroll
      for (int k = 0; k < 16; ++k) {
        float p = peL[btl][k];
        #pragma unroll
        for (int i = 0; i < 8; ++i) acc[i] += wpe[e0 + i][k] * p;
      }
      u32* dst = (u32*)&vv[(blk*32 + btl)*64 + e0];
      #pragma unroll
      for (int p = 0; p < 4; ++p) dst[p] = pk2bf(acc[2*p], acc[2*p+1]);
      if (tid < 32) {
        float s = 0.f;
        #pragma unroll
        for (int k = 0; k < 16; ++k) s += brecv[10 + k] * peL[tid][k];
        ST[blk*32 + tid] = s;
      }
    }
  } else if (blk < 260) {              // bidir = Wb @ Wb^T (4 blocks)
    float* bidir = ws_f + OFF_BIDIR;
    int q = blk - 256;
    for (int rr = 0; rr < 4; ++rr) {
      int idx = (q*4 + rr) * 256 + tid;
      int i = idx >> 6, j = idx & 63;
      float acc = 0.f;
      for (int e = 0; e < 64; ++e) acc += Wb[i*64+e] * Wb[j*64+e];
      bidir[idx] = acc;
    }
  } else if (blk == 260) {             // WrT, brp (pad16), catx
    for (int r = 0; r < 8; ++r) {
      int idx = r * 256 + tid;
      int d = idx >> 6, e = idx & 63;
      wrt[idx] = (d < 26) ? f2bf(Wrecv[e*26 + d]) : (u16)0;
    }
    if (tid < 16) ws_f[OFF_BRP + tid] = (tid < 10) ? brecv[tid] : 0.f;
    #pragma unroll
    for (int i = 0; i < 4; ++i) {
      int idx = i * 256 + tid;
      int j = idx >> 4, d = idx & 15;
      catx[idx] = (d < 10) ? f2bf(battn[j*10 + d]) : ((d == 10) ? f2bf(1.f) : (u16)0);
    }
  } else {                             // masksumInv[b][i]
    int b = blk - 261;
    int i = tid & 63, q = tid >> 6;
    float s = 0.f;
    for (int t = q*32; t < q*32 + 32; ++t) s += mask[(b*128 + t)*64 + i];
    pm[q][i] = s;
    __syncthreads();
    if (tid < 64)
      (ws_f + OFF_MS)[b*64 + tid] =
          1.0f / (pm[0][tid] + pm[1][tid] + pm[2][tid] + pm[3][tid]);
  }
}

// ---------------- K1: alpha partials + persist hTg/W1p — BARRIER-FREE ----------------
__global__ __launch_bounds__(256)
void k_adj(const float* __restrict__ x, const float* __restrict__ mask,
           const float* __restrict__ Wobs, float* __restrict__ ws_f,
           char* __restrict__ ws_b) {
  __shared__ __align__(16) u16 hA[64][72];
  __shared__ __align__(16) u16 hmA[64][24];

  const int tid = threadIdx.x;
  const int b = blockIdx.y, tc = blockIdx.x;
  const int w = tid >> 6, l = tid & 63, lr = l & 15, lq = l >> 4, kb = lq * 8;
  const int i0 = 16*w + lq*4;
  const u16* wrt  = (const u16*)(ws_b + BOFF_WRT);
  const u16* catx = (const u16*)(ws_b + BOFF_CATX);
  const u16* vv   = (const u16*)(ws_b + BOFF_V);
  const float* brp = ws_f + OFF_BRP;
  const float* ST = ws_f + OFF_ST;
  const float* bidirG = ws_f + OFF_BIDIR;

  const short8 z8 = (short8){0,0,0,0,0,0,0,0};
  const bool lowk = (lq < 2);
  short8 w0 = z8, w1 = z8;
  if (lr < 10) {
    const u16* wr = wrt + lr * 64;
    w0 = *(const short8*)&wr[kb];
    w1 = *(const short8*)&wr[32 + kb];
  }
  short8 bc[4];
  #pragma unroll
  for (int n = 0; n < 4; ++n)
    bc[n] = lowk ? *(const short8*)&catx[(16*n + lr)*16 + lq*8] : z8;
  float4 bv = *(const float4*)&brp[lq*4];
  float bidirR[4][4];
  #pragma unroll
  for (int n = 0; n < 4; ++n)
    #pragma unroll
    for (int reg = 0; reg < 4; ++reg)
      bidirR[n][reg] = bidirG[((i0+reg) << 6) + 16*n + lr];

  f32x4 asum[4];
  #pragma unroll
  for (int n = 0; n < 4; ++n) asum[n] = (f32x4){0.f,0.f,0.f,0.f};

  const int e4 = tid & 15, sg = tid >> 4;

  for (int tt = 0; tt < 8; ++tt) {
    int t = tc * 8 + tt;
    int base = b * 128 + t;
    short8 av0 = z8, av1 = z8;
    if (lr == 10) {
      av0 = *(const short8*)&vv[base*64 + kb];
      av1 = *(const short8*)&vv[base*64 + 32 + kb];
    }
    float st = ST[base];
    { // P0: h build -> hA (warp-local rows) + lane-major hTg
      float4 mk4 = *(const float4*)&mask[base*64 + sg*4];
      float mks[4] = {mk4.x, mk4.y, mk4.z, mk4.w};
      u16 hv[4][4];
      #pragma unroll
      for (int si = 0; si < 4; ++si) {
        int s = sg*4 + si;
        float4 xv = *(const float4*)&x[base*256 + s*4];
        float xo[4] = {xv.x, xv.y, xv.z, xv.w};
        float ax = 0.f, ay = 0.f, az = 0.f, aw = 0.f;
        #pragma unroll
        for (int o = 0; o < 4; ++o) {
          float4 wv = *(const float4*)&Wobs[(s*4+o)*64 + e4*4];
          ax += xo[o]*wv.x; ay += xo[o]*wv.y; az += xo[o]*wv.z; aw += xo[o]*wv.w;
        }
        float mk = mks[si];
        uint2 p;
        p.x = pk2bf(fmaxf(ax,0.f)*mk, fmaxf(ay,0.f)*mk);
        p.y = pk2bf(fmaxf(az,0.f)*mk, fmaxf(aw,0.f)*mk);
        *(uint2*)&hA[s][e4*4] = p;
        hv[si][0] = (u16)p.x; hv[si][1] = (u16)(p.x >> 16);
        hv[si][2] = (u16)p.y; hv[si][3] = (u16)(p.y >> 16);
      }
      u16* hTg = (u16*)(ws_b + BOFF_HT) + (size_t)base * 4096 + tid * 16;
      uint4 A, B;
      A.x = (u32)hv[0][0] | ((u32)hv[1][0] << 16);
      A.y = (u32)hv[2][0] | ((u32)hv[3][0] << 16);
      A.z = (u32)hv[0][1] | ((u32)hv[1][1] << 16);
      A.w = (u32)hv[2][1] | ((u32)hv[3][1] << 16);
      B.x = (u32)hv[0][2] | ((u32)hv[1][2] << 16);
      B.y = (u32)hv[2][2] | ((u32)hv[3][2] << 16);
      B.z = (u32)hv[0][3] | ((u32)hv[1][3] << 16);
      B.w = (u32)hv[2][3] | ((u32)hv[3][3] << 16);
      *(uint4*)&hTg[0] = A;
      *(uint4*)&hTg[8] = B;
    }
    { // P1: hmx (warp-local rows)
      short8 a0 = (lr < 10) ? w0 : av0;
      short8 a1 = (lr < 10) ? w1 : av1;
      f32x4 acc = (f32x4){0.f,0.f,0.f,0.f};
      short8 b0 = *(const short8*)&hA[16*w + lr][kb];
      short8 b1 = *(const short8*)&hA[16*w + lr][32 + kb];
      acc = __builtin_amdgcn_mfma_f32_16x16x32_bf16(a0, b0, acc, 0, 0, 0);
      acc = __builtin_amdgcn_mfma_f32_16x16x32_bf16(a1, b1, acc, 0, 0, 0);
      uint2 qq;
      qq.x = pk2bf(acc[0]+bv.x, acc[1]+bv.y);
      qq.y = pk2bf(acc[2]+bv.z, acc[3]+bv.w);
      *(uint2*)&hmA[16*w + lr][lq*4] = qq;
    }
    { // P2: alpha; accumulate asum; write lane-packed w1
      short8 am = lowk ? *(const short8*)&hmA[16*w + lr][lq*8] : z8;
      u32 w1u[8];
      #pragma unroll
      for (int n = 0; n < 4; ++n) {
        f32x4 z = (f32x4){st, st, st, st};
        z = __builtin_amdgcn_mfma_f32_16x16x32_bf16(am, bc[n], z, 0, 0, 0);
        float w1v[4];
        #pragma unroll
        for (int reg = 0; reg < 4; ++reg) {
          float al = fmaxf(z[reg], 0.f);
          asum[n][reg] += al;
          w1v[reg] = al * bidirR[n][reg];
        }
        w1u[2*n]   = pk2bf(w1v[0], w1v[1]);
        w1u[2*n+1] = pk2bf(w1v[2], w1v[3]);
      }
      u16* w1g = (u16*)(ws_b + BOFF_W1) + (size_t)base * 4096 + tid * 16;
      uint4 A, B;
      A.x = w1u[0]; A.y = w1u[1]; A.z = w1u[2]; A.w = w1u[3];
      B.x = w1u[4]; B.y = w1u[5]; B.z = w1u[6]; B.w = w1u[7];
      *(uint4*)&w1g[0] = A;
      *(uint4*)&w1g[8] = B;
    }
  }
  { // staged partials: adjP[tc][b][tid*16 + n*4 + reg]
    float* adjP = (float*)(ws_b + BOFF_ADJP) + (((size_t)tc * 64 + b) << 12) + tid * 16;
    #pragma unroll
    for (int n = 0; n < 4; ++n) {
      float4 A;
      A.x = asum[n][0]; A.y = asum[n][1]; A.z = asum[n][2]; A.w = asum[n][3];
      *(float4*)&adjP[n * 4] = A;
    }
  }
}

// ---------------- K1b: adjS = bf16(sum_tc adjP * msInv) ----------------
__global__ __launch_bounds__(256)
void k_scale(const float* __restrict__ ws_f, char* __restrict__ ws_b) {
  const int b = blockIdx.x, tid = threadIdx.x;
  const int w = tid >> 6, l = tid & 63, lr = l & 15, lq = l >> 4;
  const int i0 = 16*w + lq*4;
  const float* msI = ws_f + OFF_MS + b * 64;
  u16* as_ = (u16*)(ws_b + BOFF_ADJS) + (size_t)b * 4096;

  float S[16];
  #pragma unroll
  for (int k = 0; k < 16; ++k) S[k] = 0.f;
  for (int tc = 0; tc < 16; ++tc) {
    const float4* src = (const float4*)
        ((const float*)(ws_b + BOFF_ADJP) + (((size_t)tc * 64 + b) << 12) + tid * 16);
    #pragma unroll
    for (int n = 0; n < 4; ++n) {
      float4 v = src[n];
      S[n*4+0] += v.x; S[n*4+1] += v.y; S[n*4+2] += v.z; S[n*4+3] += v.w;
    }
  }
  float msr[4];
  #pragma unroll
  for (int reg = 0; reg < 4; ++reg) msr[reg] = msI[i0 + reg];
  #pragma unroll
  for (int n = 0; n < 4; ++n)
    #pragma unroll
    for (int reg = 0; reg < 4; ++reg)
      as_[(i0 + reg) * 64 + 16*n + lr] = f2bf(S[n*4 + reg] * msr[reg]);
}

// ---------------- K2: prop1+prop2 only (loads hTg/W1p/adjS) ----------------
__global__ __launch_bounds__(256, 4)
void k_main(const float* __restrict__ ws_f, const char* __restrict__ ws_b,
            u16* __restrict__ Hh) {
  __shared__ __align__(16) char smem[36864];
  u16 (*h1L)[72] = (u16 (*)[72])(smem);           // h1T [e][i]
  u16 (*hT)[72]  = (u16 (*)[72])(smem + 9216);    // h^T [e][s]
  u16 (*wA)[72]  = (u16 (*)[72])(smem + 18432);   // w1 [i][j]
  u16 (*adjS)[72]= (u16 (*)[72])(smem + 27648);

  const int tid = threadIdx.x;
  const int t = blockIdx.x, b = blockIdx.y;
  const int w = tid >> 6, l = tid & 63, lr = l & 15, lq = l >> 4, kb = lq * 8;
  const int base = b * 128 + t;
  const int i0 = 16*w + lq*4;

  const uint4* ag = (const uint4*)(ws_b + BOFF_ADJS + (size_t)b * 8192);
  uint4 g0 = ag[2*tid], g1 = ag[2*tid + 1];
  const uint4* hp = (const uint4*)((const u16*)(ws_b + BOFF_HT) + (size_t)base * 4096);
  uint4 hv0 = hp[2*tid], hv1 = hp[2*tid + 1];
  const uint4* wp = (const uint4*)((const u16*)(ws_b + BOFF_W1) + (size_t)base * 4096);
  uint4 wp0 = wp[2*tid], wp1 = wp[2*tid + 1];

  { // Pa: stage hT (lane-major unpack), wA (unpack scatter), adjS
    const int e4 = tid & 15, sg = tid >> 4;
    uint2 p0; p0.x = hv0.x; p0.y = hv0.y;
    uint2 p1; p1.x = hv0.z; p1.y = hv0.w;
    uint2 p2; p2.x = hv1.x; p2.y = hv1.y;
    uint2 p3; p3.x = hv1.z; p3.y = hv1.w;
    *(uint2*)&hT[e4*4 + 0][sg*4] = p0;
    *(uint2*)&hT[e4*4 + 1][sg*4] = p1;
    *(uint2*)&hT[e4*4 + 2][sg*4] = p2;
    *(uint2*)&hT[e4*4 + 3][sg*4] = p3;
    u32 q[8] = {wp0.x, wp0.y, wp0.z, wp0.w, wp1.x, wp1.y, wp1.z, wp1.w};
    #pragma unroll
    for (int n = 0; n < 4; ++n) {
      int j = 16*n + lr;
      u32 lo = q[2*n], hi = q[2*n+1];
      wA[i0+0][j] = (u16)lo; wA[i0+1][j] = (u16)(lo >> 16);
      wA[i0+2][j] = (u16)hi; wA[i0+3][j] = (u16)(hi >> 16);
    }
    int idx0 = 2*tid, idx1 = 2*tid + 1;
    *(uint4*)&adjS[idx0 >> 3][(idx0 & 7) * 8] = g0;
    *(uint4*)&adjS[idx1 >> 3][(idx1 & 7) * 8] = g1;
  }
  __syncthreads();

  { // Pc: h1 = relu(w1 @ h) -> h1L
    short8 aw0 = *(const short8*)&wA[16*w + lr][kb];
    short8 aw1 = *(const short8*)&wA[16*w + lr][32 + kb];
    #pragma unroll
    for (int n = 0; n < 4; ++n) {
      f32x4 acc = (f32x4){0.f,0.f,0.f,0.f};
      short8 b0 = *(const short8*)&hT[16*n + lr][kb];
      short8 b1 = *(const short8*)&hT[16*n + lr][32 + kb];
      acc = __builtin_amdgcn_mfma_f32_16x16x32_bf16(aw0, b0, acc, 0, 0, 0);
      acc = __builtin_amdgcn_mfma_f32_16x16x32_bf16(aw1, b1, acc, 0, 0, 0);
      int e = 16*n + lr;
      uint2 pp;
      pp.x = pk2bf(fmaxf(acc[0],0.f), fmaxf(acc[1],0.f));
      pp.y = pk2bf(fmaxf(acc[2],0.f), fmaxf(acc[3],0.f));
      *(uint2*)&h1L[e][i0] = pp;
    }
  }
  __syncthreads();

  { // Pd: w2 = w1 (.) adjS; h2 = relu(w2 @ h1) -> Hh
    int row = 16*w + lr;
    union { short8 v; u16 h[8]; u32 u[4]; } uw0, uw1, ud0, ud1, oa, ob;
    uw0.v = *(const short8*)&wA[row][kb];
    uw1.v = *(const short8*)&wA[row][32 + kb];
    ud0.v = *(const short8*)&adjS[row][kb];
    ud1.v = *(const short8*)&adjS[row][32 + kb];
    #pragma unroll
    for (int k = 0; k < 4; ++k) {
      oa.u[k] = pk2bf(bf2f(uw0.h[2*k])*bf2f(ud0.h[2*k]),
                      bf2f(uw0.h[2*k+1])*bf2f(ud0.h[2*k+1]));
      ob.u[k] = pk2bf(bf2f(uw1.h[2*k])*bf2f(ud1.h[2*k]),
                      bf2f(uw1.h[2*k+1])*bf2f(ud1.h[2*k+1]));
    }
    short8 a20 = oa.v, a21 = ob.v;
    size_t obase = ((size_t)b * 64) * 8192 + (size_t)t * 64;
    #pragma unroll
    for (int n = 0; n < 4; ++n) {
      f32x4 acc = (f32x4){0.f,0.f,0.f,0.f};
      short8 b0 = *(const short8*)&h1L[16*n + lr][kb];
      short8 b1 = *(const short8*)&h1L[16*n + lr][32 + kb];
      acc = __builtin_amdgcn_mfma_f32_16x16x32_bf16(a20, b0, acc, 0, 0, 0);
      acc = __builtin_amdgcn_mfma_f32_16x16x32_bf16(a21, b1, acc, 0, 0, 0);
      int e = 16*n + lr;
      u32 p0 = pk2bf(fmaxf(acc[0],0.f), fmaxf(acc[1],0.f));
      u32 p1 = pk2bf(fmaxf(acc[2],0.f), fmaxf(acc[3],0.f));
      Hh[obase + (size_t)(i0+0) * 8192 + e] = (u16)p0;
      Hh[obase + (size_t)(i0+1) * 8192 + e] = (u16)(p0 >> 16);
      Hh[obase + (size_t)(i0+2) * 8192 + e] = (u16)p1;
      Hh[obase + (size_t)(i0+3) * 8192 + e] = (u16)(p1 >> 16);
    }
  }
}

// ---------------- K3: temporal attention (512 thr; f32 Ht; uniform-wave A/E) ----------------
__global__ __launch_bounds__(512)
void k_attn(const char* __restrict__ ws_b, const u16* __restrict__ Hh,
            const float* __restrict__ Wq, const float* __restrict__ bq,
            const float* __restrict__ Wk, const float* __restrict__ bk,
            const float* __restrict__ Ws, const float* __restrict__ bs,
            const float* __restrict__ Wemb, const float* __restrict__ bemb,
            float* __restrict__ out) {
  __shared__ float HtF[128][84];       // f32, 16B-aligned rows; cols 0..63 valid
  __shared__ u16 peB[128][18];
  __shared__ float wsL[128];
  __shared__ float pA[6][80];
  __shared__ float pK[8][10];
  __shared__ float qvL[80];
  __shared__ float pC[4][128];
  __shared__ float bb[128];
  __shared__ float red[4];
  __shared__ float cstL, sWL;

  const int tid = threadIdx.x;
  const int s = blockIdx.x, b = blockIdx.y;
  const float scale = 0.111803398875f; // 1/sqrt(80)
  const u16* peh = (const u16*)(ws_b + BOFF_PEH);

  const u16* src = Hh + ((size_t)b * 64 + s) * 8192;
  #pragma unroll
  for (int r = 0; r < 2; ++r) {
    int id = r * 512 + tid;
    int tt = id >> 3, c = (id & 7) * 8;
    uint4 q = *(const uint4*)&src[tt * 64 + c];
    float4 f0, f1;
    f0.x = bf2f((u16)q.x); f0.y = bf2f((u16)(q.x >> 16));
    f0.z = bf2f((u16)q.y); f0.w = bf2f((u16)(q.y >> 16));
    f1.x = bf2f((u16)q.z); f1.y = bf2f((u16)(q.z >> 16));
    f1.z = bf2f((u16)q.w); f1.w = bf2f((u16)(q.w >> 16));
    *(float4*)&HtF[tt][c]     = f0;
    *(float4*)&HtF[tt][c + 4] = f1;
  }
  #pragma unroll
  for (int r = 0; r < 2; ++r) {
    int id = r * 512 + tid;
    u32 pv = ((const u32*)(peh + (size_t)b * 2048))[id];
    *(u32*)&peB[id >> 3][(id & 7) * 2] = pv;
  }
  if (tid < 128) wsL[tid] = Ws[tid];
  __syncthreads();

  // Phase A: hbar partials, wave-uniform (384 H-threads, 96 PE-threads)
  if (tid < 384) {
    int d = tid & 63, c = tid >> 6;
    int t0 = c * 22, t1 = (t0 + 22 > 128) ? 128 : t0 + 22;
    float a0 = 0.f, a1 = 0.f, a2 = 0.f, a3 = 0.f;
    int t = t0;
    for (; t + 4 <= t1; t += 4) {
      a0 += wsL[t]   * HtF[t][d];
      a1 += wsL[t+1] * HtF[t+1][d];
      a2 += wsL[t+2] * HtF[t+2][d];
      a3 += wsL[t+3] * HtF[t+3][d];
    }
    for (; t < t1; ++t) a0 += wsL[t] * HtF[t][d];
    pA[c][d] = (a0 + a1) + (a2 + a3);
  } else if (tid < 480) {
    int idx = tid - 384;
    int k = idx & 15, c = idx >> 4;
    int t0 = c * 22, t1 = (t0 + 22 > 128) ? 128 : t0 + 22;
    float a0 = 0.f, a1 = 0.f, a2 = 0.f, a3 = 0.f;
    int t = t0;
    for (; t + 4 <= t1; t += 4) {
      a0 += wsL[t]   * bf2f(peB[t][k]);
      a1 += wsL[t+1] * bf2f(peB[t+1][k]);
      a2 += wsL[t+2] * bf2f(peB[t+2][k]);
      a3 += wsL[t+3] * bf2f(peB[t+3][k]);
    }
    for (; t < t1; ++t) a0 += wsL[t] * bf2f(peB[t][k]);
    pA[c][64 + k] = (a0 + a1) + (a2 + a3);
  } else if (tid == 480) {
    float a0 = 0.f, a1 = 0.f, a2 = 0.f, a3 = 0.f;
    for (int t = 0; t < 128; t += 4) {
      a0 += wsL[t]; a1 += wsL[t+1]; a2 += wsL[t+2]; a3 += wsL[t+3];
    }
    sWL = (a0 + a1) + (a2 + a3);
  }
  __syncthreads();

  if (tid < 80) {
    int a = tid % 10, c = tid / 10;
    float a0 = 0.f, a1 = 0.f;
    #pragma unroll
    for (int i = 0; i < 10; i += 2) {
      int d = c * 10 + i;
      float h0 = pA[0][d] + pA[1][d] + pA[2][d] + pA[3][d] + pA[4][d] + pA[5][d];
      float h1 = pA[0][d+1] + pA[1][d+1] + pA[2][d+1] + pA[3][d+1] + pA[4][d+1] + pA[5][d+1];
      a0 += h0 * Wk[d * 10 + a];
      a1 += h1 * Wk[(d+1) * 10 + a];
    }
    pK[c][a] = a0 + a1;
  }
  __syncthreads();

  if (tid <= 80) {
    float kt[10];
    #pragma unroll
    for (int a = 0; a < 10; ++a) {
      float acc = sWL * bk[a];
      #pragma unroll
      for (int c = 0; c < 8; ++c) acc += pK[c][a];
      kt[a] = acc;
    }
    if (tid < 80) {
      float a0 = 0.f, a1 = 0.f;
      #pragma unroll
      for (int a = 0; a < 10; a += 2) {
        a0 += Wq[tid * 10 + a] * kt[a];
        a1 += Wq[tid * 10 + a + 1] * kt[a + 1];
      }
      qvL[tid] = a0 + a1;
    } else {
      float cq = 0.f;
      #pragma unroll
      for (int a = 0; a < 10; ++a) cq += bq[a] * kt[a];
      cstL = scale * cq + bs[0];
    }
  }
  __syncthreads();

  // Phase C: beta partials; H = exactly 16 float4 iters (q0:0-5, q1:6-11, q2:12-15), q3 = PE
  {
    int t = tid & 127, q = tid >> 7;
    float a0 = 0.f, a1 = 0.f, a2 = 0.f, a3 = 0.f;
    const float4* row = (const float4*)&HtF[t][0];
    if (q == 0) {
      #pragma unroll
      for (int i = 0; i < 6; ++i) {
        float4 f = row[i];
        a0 += f.x * qvL[4*i];   a1 += f.y * qvL[4*i+1];
        a2 += f.z * qvL[4*i+2]; a3 += f.w * qvL[4*i+3];
      }
    } else if (q == 1) {
      #pragma unroll
      for (int i = 6; i < 12; ++i) {
        float4 f = row[i];
        a0 += f.x * qvL[4*i];   a1 += f.y * qvL[4*i+1];
        a2 += f.z * qvL[4*i+2]; a3 += f.w * qvL[4*i+3];
      }
    } else if (q == 2) {
      #pragma unroll
      for (int i = 12; i < 16; ++i) {
        float4 f = row[i];
        a0 += f.x * qvL[4*i];   a1 += f.y * qvL[4*i+1];
        a2 += f.z * qvL[4*i+2]; a3 += f.w * qvL[4*i+3];
      }
    } else {
      #pragma unroll
      for (int k = 0; k < 16; k += 4) {
        a0 += bf2f(peB[t][k])   * qvL[64 + k];
        a1 += bf2f(peB[t][k+1]) * qvL[65 + k];
        a2 += bf2f(peB[t][k+2]) * qvL[66 + k];
        a3 += bf2f(peB[t][k+3]) * qvL[67 + k];
      }
    }
    pC[q][t] = (a0 + a1) + (a2 + a3);
  }
  __syncthreads();

  if (tid < 128) {
    float v = scale * (pC[0][tid] + pC[1][tid] + pC[2][tid] + pC[3][tid]) + cstL;
    bb[tid] = v;
    float mm = v;
    #pragma unroll
    for (int off = 32; off; off >>= 1) mm = fmaxf(mm, __shfl_xor(mm, off));
    if ((tid & 63) == 0) red[tid >> 6] = mm;
  }
  __syncthreads();
  float mx = fmaxf(red[0], red[1]);
  if (tid < 128) {
    float ev = expf(bb[tid] - mx);
    bb[tid] = ev;
    float ss = ev;
    #pragma unroll
    for (int off = 32; off; off >>= 1) ss += __shfl_xor(ss, off);
    if ((tid & 63) == 0) red[2 + (tid >> 6)] = ss;
  }
  __syncthreads();

  // Phase E: hout partials (reuse pA), wave-uniform mapping
  if (tid < 384) {
    int d = tid & 63, c = tid >> 6;
    int t0 = c * 22, t1 = (t0 + 22 > 128) ? 128 : t0 + 22;
    float a0 = 0.f, a1 = 0.f, a2 = 0.f, a3 = 0.f;
    int t = t0;
    for (; t + 4 <= t1; t += 4) {
      a0 += bb[t]   * HtF[t][d];
      a1 += bb[t+1] * HtF[t+1][d];
      a2 += bb[t+2] * HtF[t+2][d];
      a3 += bb[t+3] * HtF[t+3][d];
    }
    for (; t < t1; ++t) a0 += bb[t] * HtF[t][d];
    pA[c][d] = (a0 + a1) + (a2 + a3);
  } else if (tid < 480) {
    int idx = tid - 384;
    int k = idx & 15, c = idx >> 4;
    int t0 = c * 22, t1 = (t0 + 22 > 128) ? 128 : t0 + 22;
    float a0 = 0.f, a1 = 0.f, a2 = 0.f, a3 = 0.f;
    int t = t0;
    for (; t + 4 <= t1; t += 4) {
      a0 += bb[t]   * bf2f(peB[t][k]);
      a1 += bb[t+1] * bf2f(peB[t+1][k]);
      a2 += bb[t+2] * bf2f(peB[t+2][k]);
      a3 += bb[t+3] * bf2f(peB[t+3][k]);
    }
    for (; t < t1; ++t) a0 += bb[t] * bf2f(peB[t][k]);
    pA[c][64 + k] = (a0 + a1) + (a2 + a3);
  }
  __syncthreads();

  // Phase F: out partials over 4 d-chunks of 20 (reuse pC)
  {
    int o = tid & 127, q = tid >> 7;
    int d0 = q * 20;
    float a0 = 0.f, a1 = 0.f, a2 = 0.f, a3 = 0.f;
    #pragma unroll
    for (int i = 0; i < 20; i += 4) {
      int d = d0 + i;
      float h0 = pA[0][d]   + pA[1][d]   + pA[2][d]   + pA[3][d]   + pA[4][d]   + pA[5][d];
      float h1 = pA[0][d+1] + pA[1][d+1] + pA[2][d+1] + pA[3][d+1] + pA[4][d+1] + pA[5][d+1];
      float h2 = pA[0][d+2] + pA[1][d+2] + pA[2][d+2] + pA[3][d+2] + pA[4][d+2] + pA[5][d+2];
      float h3 = pA[0][d+3] + pA[1][d+3] + pA[2][d+3] + pA[3][d+3] + pA[4][d+3] + pA[5][d+3];
      a0 += h0 * Wemb[d * 128 + o];
      a1 += h1 * Wemb[(d+1) * 128 + o];
      a2 += h2 * Wemb[(d+2) * 128 + o];
      a3 += h3 * Wemb[(d+3) * 128 + o];
    }
    pC[q][o] = (a0 + a1) + (a2 + a3);
  }
  __syncthreads();
  if (tid < 128) {
    float rdenom = 1.0f / (red[2] + red[3]);
    out[(((size_t)b * 64 + s) << 7) + tid] =
        bemb[tid] + (pC[0][tid] + pC[1][tid] + pC[2][tid] + pC[3][tid]) * rdenom;
  }
}

extern "C" void kernel_launch(void* const* d_in, const int* in_sizes, int n_in,
                              void* d_out, int out_size, void* d_ws, size_t ws_size,
                              hipStream_t stream) {
  (void)in_sizes; (void)n_in; (void)out_size; (void)ws_size;
  const float* x     = (const float*)d_in[0];
  const float* times = (const float*)d_in[1];
  const float* mask  = (const float*)d_in[2];
  const float* Wobs  = (const float*)d_in[3];
  const float* Wattn = (const float*)d_in[4];
  const float* Wrecv = (const float*)d_in[5];
  const float* brecv = (const float*)d_in[6];
  const float* Wb    = (const float*)d_in[7];
  const float* Wq    = (const float*)d_in[8];
  const float* bq    = (const float*)d_in[9];
  const float* Wk    = (const float*)d_in[10];
  const float* bk    = (const float*)d_in[11];
  const float* Ws    = (const float*)d_in[12];
  const float* bs    = (const float*)d_in[13];
  const float* Wemb  = (const float*)d_in[14];
  const float* bemb  = (const float*)d_in[15];
  float* out = (float*)d_out;
  float* ws_f = (float*)d_ws;
  char* ws_b = (char*)d_ws;
  u16* Hh = (u16*)(ws_b + BOFF_HH);

  k_pre<<<325, 256, 0, stream>>>(times, mask, Wb, Wrecv, brecv, Wattn, ws_f, ws_b);
  k_adj<<<dim3(16, 64), 256, 0, stream>>>(x, mask, Wobs, ws_f, ws_b);
  k_scale<<<64, 256, 0, stream>>>(ws_f, ws_b);
  k_main<<<dim3(128, 64), 256, 0, stream>>>(ws_f, ws_b, Hh);
  k_attn<<<dim3(64, 64), 512, 0, stream>>>(ws_b, Hh, Wq, bq, Wk, bk, Ws, bs, Wemb, bemb, out);
}